// Round 1
// baseline (9529.840 us; speedup 1.0000x reference)
//
#include <hip/hip_runtime.h>
#include <math.h>

#define LL 1024
#define DD 512
#define HSS 64
#define QB 16
#define KB 64

// ---------------- embedding concat ----------------
__global__ void embed_kernel(const int* __restrict__ stage, const int* __restrict__ egoc,
                             const int* __restrict__ oppc, const int* __restrict__ egoa,
                             const int* __restrict__ oppa,
                             const float* __restrict__ gamestate, const float* __restrict__ controller,
                             const float* __restrict__ emb_stage, const float* __restrict__ emb_char,
                             const float* __restrict__ emb_action,
                             float* __restrict__ xin) {
  int t = blockIdx.x;
  int c = threadIdx.x;
  if (c >= 200) return;
  float v;
  if (c < 8)        v = emb_stage[stage[t] * 8 + c];
  else if (c < 24)  v = emb_char[egoc[t] * 16 + (c - 8)];
  else if (c < 40)  v = emb_char[oppc[t] * 16 + (c - 24)];
  else if (c < 72)  v = emb_action[egoa[t] * 32 + (c - 40)];
  else if (c < 104) v = emb_action[oppa[t] * 32 + (c - 72)];
  else if (c < 168) v = gamestate[t * 64 + (c - 104)];
  else              v = controller[t * 32 + (c - 168)];
  xin[t * 200 + c] = v;
}

// ---------------- layernorm (one wave per row) ----------------
__global__ void ln_kernel(const float* __restrict__ in, int ldi,
                          float* __restrict__ out, int ldo,
                          const float* __restrict__ w, const float* __restrict__ b,
                          int d) {
  int wid = threadIdx.x >> 6;
  int lane = threadIdx.x & 63;
  int row = blockIdx.x * 4 + wid;
  const float* ip = in + (size_t)row * ldi;
  float v[9];
  int n = 0;
  float s = 0.f;
  for (int c = lane; c < d; c += 64) { v[n] = ip[c]; s += v[n]; n++; }
  #pragma unroll
  for (int o = 32; o; o >>= 1) s += __shfl_xor(s, o);
  float mu = s / (float)d;
  float q = 0.f;
  for (int i = 0; i < n; i++) { float t = v[i] - mu; q += t * t; }
  #pragma unroll
  for (int o = 32; o; o >>= 1) q += __shfl_xor(q, o);
  float rstd = rsqrtf(q / (float)d + 1e-5f);
  float* op = out + (size_t)row * ldo;
  int c = lane;
  for (int i = 0; i < n; i++, c += 64) op[c] = (v[i] - mu) * rstd * w[c] + b[c];
}

// ---------------- SGEMM: C[M,N] (+)= act(A[M,K] @ W[K,N] + bias) ----------------
// BM=128, BN=64, BK=16, 256 threads, 8x4 per thread. flags: 1=accumulate, 2=gelu
__global__ __launch_bounds__(256) void sgemm_kernel(
    const float* __restrict__ A, int lda,
    const float* __restrict__ W,
    const float* __restrict__ bias,
    float* __restrict__ C, int ldc,
    int M, int N, int K, int flags) {
  __shared__ float As[16][132];  // pad 132: store bank-spread, rows 16B-aligned
  __shared__ float Bs[16][64];
  int t = threadIdx.x;
  int tx = t & 15, ty = t >> 4;
  int row0 = blockIdx.y * 128;
  int col0 = blockIdx.x * 64;
  float acc[8][4];
  #pragma unroll
  for (int i = 0; i < 8; i++)
    #pragma unroll
    for (int j = 0; j < 4; j++) acc[i][j] = 0.f;

  for (int kt = 0; kt < K; kt += 16) {
    #pragma unroll
    for (int rep = 0; rep < 8; rep++) {
      int idx = rep * 256 + t;
      int r = idx >> 4, k = idx & 15;
      int kk = kt + k;
      As[k][r] = (kk < K) ? A[(size_t)(row0 + r) * lda + kk] : 0.f;
    }
    #pragma unroll
    for (int rep = 0; rep < 4; rep++) {
      int idx = rep * 256 + t;
      int k = idx >> 6, c = idx & 63;
      int kk = kt + k;
      Bs[k][c] = (kk < K && col0 + c < N) ? W[(size_t)kk * N + col0 + c] : 0.f;
    }
    __syncthreads();
    #pragma unroll
    for (int kk = 0; kk < 16; kk++) {
      float4 a0 = *(const float4*)&As[kk][ty * 8];
      float4 a1 = *(const float4*)&As[kk][ty * 8 + 4];
      float4 b0 = *(const float4*)&Bs[kk][tx * 4];
      float a[8] = {a0.x, a0.y, a0.z, a0.w, a1.x, a1.y, a1.z, a1.w};
      float bv[4] = {b0.x, b0.y, b0.z, b0.w};
      #pragma unroll
      for (int i = 0; i < 8; i++)
        #pragma unroll
        for (int j = 0; j < 4; j++) acc[i][j] += a[i] * bv[j];
    }
    __syncthreads();
  }
  #pragma unroll
  for (int i = 0; i < 8; i++) {
    int r = row0 + ty * 8 + i;
    #pragma unroll
    for (int j = 0; j < 4; j++) {
      int c = col0 + tx * 4 + j;
      if (c < N) {
        float v = acc[i][j] + bias[c];
        if (flags & 2) v = 0.5f * v * (1.f + erff(v * 0.70710678118f));
        float* p = &C[(size_t)r * ldc + c];
        if (flags & 1) *p += v; else *p = v;
      }
    }
  }
}

// ---------------- fused causal attention with relative positions ----------------
// score(l,j) = (q_l·k_j + q_l·Er[1023-(l-j)]) * 0.125 for j<=l; online softmax.
__global__ __launch_bounds__(256) void attn_kernel(
    const float* __restrict__ qkv,   // [4096, 1536]
    const float* __restrict__ Er,    // [1024, 64] (this layer)
    float* __restrict__ y) {         // [4096, 512]
  __shared__ float Qs[QB][HSS];            // broadcast reads
  __shared__ float Ks[KB][HSS + 1];        // 2-way on lane=jj reads
  __shared__ float Vs[KB][HSS];            // lane=d reads, conflict-free
  __shared__ float Es[QB + KB - 1][HSS + 1];
  __shared__ float Ps[QB][KB];

  int l0 = blockIdx.x * QB;
  int h = blockIdx.y;
  int b = blockIdx.z;
  int t = threadIdx.x;
  int lane = t & 63;
  int w = t >> 6;
  const size_t rowbase = (size_t)(b * LL) * 1536;

  {  // load Q block
    int ql = t >> 4;
    int c = (t & 15) * 4;
    const float* src = qkv + rowbase + (size_t)(l0 + ql) * 1536 + h * HSS + c;
    float4 v = *(const float4*)src;
    Qs[ql][c] = v.x; Qs[ql][c + 1] = v.y; Qs[ql][c + 2] = v.z; Qs[ql][c + 3] = v.w;
  }

  float m[4], sum[4], acc[4], corr[4];
  #pragma unroll
  for (int s = 0; s < 4; s++) { m[s] = -INFINITY; sum[s] = 0.f; acc[s] = 0.f; }

  int ntiles = (l0 + QB + KB - 1) / KB;
  for (int tile = 0; tile < ntiles; tile++) {
    int j0 = tile * KB;
    __syncthreads();  // protect prev tile's LDS (and publish Qs on tile 0)
    #pragma unroll
    for (int rep = 0; rep < 4; rep++) {
      int idx = rep * 256 + t;
      int r = idx >> 4;
      int c = (idx & 15) * 4;
      const float* kp = qkv + rowbase + (size_t)(j0 + r) * 1536 + 512 + h * HSS + c;
      float4 kv = *(const float4*)kp;
      Ks[r][c] = kv.x; Ks[r][c + 1] = kv.y; Ks[r][c + 2] = kv.z; Ks[r][c + 3] = kv.w;
      const float* vp = qkv + rowbase + (size_t)(j0 + r) * 1536 + 1024 + h * HSS + c;
      *(float4*)&Vs[r][c] = *(const float4*)vp;
    }
    int e0 = 1008 - l0 + j0;  // 1023-(l0+QB-1)+j0, always >= 0
    for (int idx = t; idx < (QB + KB - 1) * HSS; idx += 256) {
      int r = idx >> 6;
      int c = idx & 63;
      int er = e0 + r;
      Es[r][c] = (er < LL) ? Er[(size_t)er * HSS + c] : 0.f;
    }
    __syncthreads();

    int jj = lane;
    int j = j0 + jj;
    #pragma unroll
    for (int s = 0; s < 4; s++) {
      int ql = w * 4 + s;
      int l = l0 + ql;
      int r = jj + (QB - 1) - ql;
      float sc = 0.f;
      #pragma unroll 8
      for (int d = 0; d < HSS; d++)
        sc += Qs[ql][d] * (Ks[jj][d] + Es[r][d]);
      sc *= 0.125f;
      if (j > l) sc = -INFINITY;
      float mloc = sc;
      #pragma unroll
      for (int o = 32; o; o >>= 1) mloc = fmaxf(mloc, __shfl_xor(mloc, o));
      float mnew = fmaxf(m[s], mloc);
      bool valid = (mnew != -INFINITY);
      float mm = valid ? mnew : 0.f;
      float cr = valid ? __expf(m[s] - mm) : 1.f;   // m=-inf -> 0
      float p = __expf(sc - mm);                    // masked -> 0
      float ps = p;
      #pragma unroll
      for (int o = 32; o; o >>= 1) ps += __shfl_xor(ps, o);
      sum[s] = sum[s] * cr + ps;
      if (valid) m[s] = mnew;
      corr[s] = cr;
      Ps[ql][jj] = p;  // same-wave consumer only
    }
    #pragma unroll
    for (int s = 0; s < 4; s++) {
      int ql = w * 4 + s;
      float a = 0.f;
      #pragma unroll 8
      for (int jj2 = 0; jj2 < KB; jj2++)
        a += Ps[ql][jj2] * Vs[jj2][lane];
      acc[s] = acc[s] * corr[s] + a;
    }
  }
  #pragma unroll
  for (int s = 0; s < 4; s++) {
    int ql = w * 4 + s;
    y[(size_t)(b * LL + l0 + ql) * DD + h * HSS + lane] = acc[s] / sum[s];
  }
}

// ---------------- extract heads region to output ----------------
__global__ void extract_kernel(const float* __restrict__ xcat, float* __restrict__ out) {
  int t = blockIdx.x;
  int c = threadIdx.x;
  if (c < 58) out[(size_t)t * 58 + c] = xcat[(size_t)t * 576 + 512 + c];
}

extern "C" void kernel_launch(void* const* d_in, const int* in_sizes, int n_in,
                              void* d_out, int out_size, void* d_ws, size_t ws_size,
                              hipStream_t stream) {
  const int* stage = (const int*)d_in[0];
  const int* egoc  = (const int*)d_in[1];
  const int* oppc  = (const int*)d_in[2];
  const int* egoa  = (const int*)d_in[3];
  const int* oppa  = (const int*)d_in[4];
  const float* gamestate  = (const float*)d_in[5];
  const float* controller = (const float*)d_in[6];
  const float* emb_stage  = (const float*)d_in[7];
  const float* emb_char   = (const float*)d_in[8];
  const float* emb_action = (const float*)d_in[9];
  const float* Wd = (const float*)d_in[10];
  const float* bd = (const float*)d_in[11];
  const float* ln1w = (const float*)d_in[12];
  const float* ln1b = (const float*)d_in[13];
  const float* Wqkv = (const float*)d_in[14];
  const float* bqkv = (const float*)d_in[15];
  const float* Wo = (const float*)d_in[16];
  const float* bo = (const float*)d_in[17];
  const float* Er = (const float*)d_in[18];
  const float* ln2w = (const float*)d_in[19];
  const float* ln2b = (const float*)d_in[20];
  const float* Wfc = (const float*)d_in[21];
  const float* bfc = (const float*)d_in[22];
  const float* Wp = (const float*)d_in[23];
  const float* bp = (const float*)d_in[24];
  const float* lnfw = (const float*)d_in[25];
  const float* lnfb = (const float*)d_in[26];

  float* ws = (float*)d_ws;
  // region0 (8,388,608 floats): xin+qkv, later aliased by ff and hln
  float* xin = ws;
  float* qkv = ws + 819200;
  float* ff  = ws;
  float* hln = ws;
  float* x    = ws + 8388608;
  float* h    = x + 2097152;
  float* y    = h + 2097152;
  float* xcat = y + 2097152;          // [4096,576]
  float* hh   = xcat + 2359296;       // [4096,288]
  float* out  = (float*)d_out;

  auto gemm = [&](const float* A, int lda, const float* W, const float* bias,
                  float* C, int ldc, int N, int K, int flags) {
    dim3 g((N + 63) / 64, 4096 / 128);
    sgemm_kernel<<<g, 256, 0, stream>>>(A, lda, W, bias, C, ldc, 4096, N, K, flags);
  };
  auto ln = [&](const float* in, int ldi, float* outp, int ldo,
                const float* w, const float* b, int d) {
    ln_kernel<<<1024, 256, 0, stream>>>(in, ldi, outp, ldo, w, b, d);
  };

  embed_kernel<<<4096, 256, 0, stream>>>(stage, egoc, oppc, egoa, oppa, gamestate,
                                         controller, emb_stage, emb_char, emb_action, xin);
  gemm(xin, 200, Wd, bd, x, 512, 512, 200, 0);

  for (int i = 0; i < 6; i++) {
    ln(x, 512, h, 512, ln1w + i * 512, ln1b + i * 512, 512);
    gemm(h, 512, Wqkv + (size_t)i * 512 * 1536, bqkv + i * 1536, qkv, 1536, 1536, 512, 0);
    attn_kernel<<<dim3(64, 8, 4), 256, 0, stream>>>(qkv, Er + (size_t)i * 1024 * 64, y);
    gemm(y, 512, Wo + (size_t)i * 512 * 512, bo + i * 512, x, 512, 512, 512, 1);
    ln(x, 512, h, 512, ln2w + i * 512, ln2b + i * 512, 512);
    gemm(h, 512, Wfc + (size_t)i * 512 * 2048, bfc + i * 2048, ff, 2048, 2048, 512, 2);
    gemm(ff, 2048, Wp + (size_t)i * 2048 * 512, bp + i * 512, x, 512, 512, 2048, 1);
  }

  ln(x, 512, xcat, 576, lnfw, lnfb, 512);

  // heads: (lnw,lnb,W1,b1,W2,b2) at d_in[27..50]
  const float* hp[24];
  for (int k = 0; k < 24; k++) hp[k] = (const float*)d_in[27 + k];
  const int din[4]  = {512, 533, 554, 566};
  const int dh[4]   = {256, 266, 277, 283};
  const int dout[4] = {21, 21, 12, 4};
  int col = 512;
  for (int hd = 0; hd < 4; hd++) {
    const float* lw = hp[hd * 6 + 0];
    const float* lb = hp[hd * 6 + 1];
    const float* W1 = hp[hd * 6 + 2];
    const float* b1 = hp[hd * 6 + 3];
    const float* W2 = hp[hd * 6 + 4];
    const float* b2 = hp[hd * 6 + 5];
    ln(xcat, 576, hln, 576, lw, lb, din[hd]);
    gemm(hln, 576, W1, b1, hh, 288, dh[hd], din[hd], 2);
    gemm(hh, 288, W2, b2, xcat + col, 576, dout[hd], dh[hd], 0);
    col += dout[hd];
  }

  extract_kernel<<<4096, 64, 0, stream>>>(xcat, out);
}

// Round 2
// 2186.006 us; speedup vs baseline: 4.3595x; 4.3595x over previous
//
#include <hip/hip_runtime.h>
#include <math.h>

typedef unsigned short u16;
typedef __bf16 bf16x8 __attribute__((ext_vector_type(8)));
typedef short s16x8 __attribute__((ext_vector_type(8)));
typedef float f32x4 __attribute__((ext_vector_type(4)));

__device__ __forceinline__ u16 f2b(float f) {
  union { float f; unsigned u; } x; x.f = f;
  unsigned r = x.u + 0x7fff + ((x.u >> 16) & 1);
  return (u16)(r >> 16);
}

__device__ __forceinline__ void gload16(const void* g, void* l) {
  __builtin_amdgcn_global_load_lds((const __attribute__((address_space(1))) unsigned int*)g,
                                   (__attribute__((address_space(3))) unsigned int*)l, 16, 0, 0);
}

// ---------------- embedding concat ----------------
__global__ void embed_kernel(const int* __restrict__ stage, const int* __restrict__ egoc,
                             const int* __restrict__ oppc, const int* __restrict__ egoa,
                             const int* __restrict__ oppa,
                             const float* __restrict__ gamestate, const float* __restrict__ controller,
                             const float* __restrict__ emb_stage, const float* __restrict__ emb_char,
                             const float* __restrict__ emb_action,
                             float* __restrict__ xin) {
  int t = blockIdx.x;
  int c = threadIdx.x;
  if (c >= 200) return;
  float v;
  if (c < 8)        v = emb_stage[stage[t] * 8 + c];
  else if (c < 24)  v = emb_char[egoc[t] * 16 + (c - 8)];
  else if (c < 40)  v = emb_char[oppc[t] * 16 + (c - 24)];
  else if (c < 72)  v = emb_action[egoa[t] * 32 + (c - 40)];
  else if (c < 104) v = emb_action[oppa[t] * 32 + (c - 72)];
  else if (c < 168) v = gamestate[t * 64 + (c - 104)];
  else              v = controller[t * 32 + (c - 168)];
  xin[t * 200 + c] = v;
}

// ---------------- layernorm (one wave per row); T = float or u16(bf16) ----------------
template<typename T>
__global__ void ln_kernel(const float* __restrict__ in, int ldi,
                          T* __restrict__ out, int ldo,
                          const float* __restrict__ w, const float* __restrict__ b,
                          int d) {
  int wid = threadIdx.x >> 6;
  int lane = threadIdx.x & 63;
  int row = blockIdx.x * 4 + wid;
  const float* ip = in + (size_t)row * ldi;
  float v[9];
  int n = 0;
  float s = 0.f;
  for (int c = lane; c < d; c += 64) { v[n] = ip[c]; s += v[n]; n++; }
  #pragma unroll
  for (int o = 32; o; o >>= 1) s += __shfl_xor(s, o);
  float mu = s / (float)d;
  float q = 0.f;
  for (int i = 0; i < n; i++) { float t = v[i] - mu; q += t * t; }
  #pragma unroll
  for (int o = 32; o; o >>= 1) q += __shfl_xor(q, o);
  float rstd = rsqrtf(q / (float)d + 1e-5f);
  T* op = out + (size_t)row * ldo;
  int c = lane;
  for (int i = 0; i < n; i++, c += 64) {
    float val = (v[i] - mu) * rstd * w[c] + b[c];
    if constexpr (sizeof(T) == 2) op[c] = f2b(val); else op[c] = val;
  }
}

// ---------------- fp32 SGEMM (embed proj + heads only) ----------------
__global__ __launch_bounds__(256) void sgemm_kernel(
    const float* __restrict__ A, int lda,
    const float* __restrict__ W,
    const float* __restrict__ bias,
    float* __restrict__ C, int ldc,
    int M, int N, int K, int flags) {
  __shared__ float As[16][132];
  __shared__ float Bs[16][64];
  int t = threadIdx.x;
  int tx = t & 15, ty = t >> 4;
  int row0 = blockIdx.y * 128;
  int col0 = blockIdx.x * 64;
  float acc[8][4];
  #pragma unroll
  for (int i = 0; i < 8; i++)
    #pragma unroll
    for (int j = 0; j < 4; j++) acc[i][j] = 0.f;

  for (int kt = 0; kt < K; kt += 16) {
    #pragma unroll
    for (int rep = 0; rep < 8; rep++) {
      int idx = rep * 256 + t;
      int r = idx >> 4, k = idx & 15;
      int kk = kt + k;
      As[k][r] = (kk < K) ? A[(size_t)(row0 + r) * lda + kk] : 0.f;
    }
    #pragma unroll
    for (int rep = 0; rep < 4; rep++) {
      int idx = rep * 256 + t;
      int k = idx >> 6, c = idx & 63;
      int kk = kt + k;
      Bs[k][c] = (kk < K && col0 + c < N) ? W[(size_t)kk * N + col0 + c] : 0.f;
    }
    __syncthreads();
    #pragma unroll
    for (int kk = 0; kk < 16; kk++) {
      float4 a0 = *(const float4*)&As[kk][ty * 8];
      float4 a1 = *(const float4*)&As[kk][ty * 8 + 4];
      float4 b0 = *(const float4*)&Bs[kk][tx * 4];
      float a[8] = {a0.x, a0.y, a0.z, a0.w, a1.x, a1.y, a1.z, a1.w};
      float bv[4] = {b0.x, b0.y, b0.z, b0.w};
      #pragma unroll
      for (int i = 0; i < 8; i++)
        #pragma unroll
        for (int j = 0; j < 4; j++) acc[i][j] += a[i] * bv[j];
    }
    __syncthreads();
  }
  #pragma unroll
  for (int i = 0; i < 8; i++) {
    int r = row0 + ty * 8 + i;
    #pragma unroll
    for (int j = 0; j < 4; j++) {
      int c = col0 + tx * 4 + j;
      if (c < N) {
        float v = acc[i][j] + bias[c];
        if (flags & 2) v = 0.5f * v * (1.f + erff(v * 0.70710678118f));
        float* p = &C[(size_t)r * ldc + c];
        if (flags & 1) *p += v; else *p = v;
      }
    }
  }
}

// ---------------- weight transpose + fp32->bf16: in [K,N] -> out [N,K] ----------------
__global__ void tpose_kernel(const float* __restrict__ in, u16* __restrict__ out, int K, int N) {
  __shared__ float tile[32][33];
  int n0 = blockIdx.x * 32, k0 = blockIdx.y * 32;
  int tx = threadIdx.x & 31, ty = threadIdx.x >> 5;
  #pragma unroll
  for (int q = 0; q < 4; q++)
    tile[ty + q * 8][tx] = in[(size_t)(k0 + ty + q * 8) * N + n0 + tx];
  __syncthreads();
  #pragma unroll
  for (int q = 0; q < 4; q++)
    out[(size_t)(n0 + ty + q * 8) * K + k0 + tx] = f2b(tile[tx][ty + q * 8]);
}

__global__ void b16conv_kernel(const float* __restrict__ in, u16* __restrict__ out, int n) {
  int i = blockIdx.x * 256 + threadIdx.x;
  if (i < n) out[i] = f2b(in[i]);
}

// ---------------- bf16 MFMA GEMM: C = act(A[M,K] @ Bt[N,K]^T + bias) ----------------
// BM=128, BK=32, 256 threads, 4 waves (2x2), wave tile 64 x (BN/2).
// flags: 1 = Cf += v, 2 = gelu, 8 = Cb(bf16) = v
template<int BN>
__global__ __launch_bounds__(256, 2) void mgemm_kernel(
    const u16* __restrict__ A, const u16* __restrict__ Bt, const float* __restrict__ bias,
    float* __restrict__ Cf, u16* __restrict__ Cb, int K, int ldc, int flags) {
  constexpr int NR = BN / 32;          // 16-col fragments per wave
  __shared__ u16 As[2][128 * 32];
  __shared__ u16 Bs[2][BN * 32];
  const int t = threadIdx.x;
  const int row0 = blockIdx.y * 128;
  const int col0 = blockIdx.x * BN;
  const int lane = t & 63, wv = t >> 6;
  const int wr = wv >> 1, wc = wv & 1;
  const int lr = lane & 15, lk = lane >> 4;

  f32x4 acc[4][NR];
  #pragma unroll
  for (int m = 0; m < 4; m++)
    #pragma unroll
    for (int n = 0; n < NR; n++) acc[m][n] = (f32x4){0.f, 0.f, 0.f, 0.f};

  auto stage = [&](int buf, int kt) {
    #pragma unroll
    for (int r = 0; r < 2; r++) {
      int c = t + 256 * r;
      gload16(A + (size_t)(row0 + (c >> 2)) * K + kt + (c & 3) * 8, &As[buf][c * 8]);
    }
    #pragma unroll
    for (int r = 0; r < BN / 64; r++) {
      int c = t + 256 * r;
      gload16(Bt + (size_t)(col0 + (c >> 2)) * K + kt + (c & 3) * 8, &Bs[buf][c * 8]);
    }
  };

  stage(0, 0);
  const int nt = K >> 5;
  const int abase = (wr * 64 + lr) * 32 + lk * 8;
  const int bbase = (wc * (BN / 2) + lr) * 32 + lk * 8;
  for (int tile = 0; tile < nt; tile++) {
    __syncthreads();
    int cur = tile & 1;
    if (tile + 1 < nt) stage(cur ^ 1, (tile + 1) * 32);
    bf16x8 af[4], bfr[NR];
    #pragma unroll
    for (int m = 0; m < 4; m++) af[m] = *(const bf16x8*)&As[cur][abase + m * 16 * 32];
    #pragma unroll
    for (int n = 0; n < NR; n++) bfr[n] = *(const bf16x8*)&Bs[cur][bbase + n * 16 * 32];
    #pragma unroll
    for (int m = 0; m < 4; m++)
      #pragma unroll
      for (int n = 0; n < NR; n++)
        acc[m][n] = __builtin_amdgcn_mfma_f32_16x16x32_bf16(af[m], bfr[n], acc[m][n], 0, 0, 0);
  }
  #pragma unroll
  for (int m = 0; m < 4; m++) {
    int row = row0 + wr * 64 + m * 16 + lk * 4;
    #pragma unroll
    for (int n = 0; n < NR; n++) {
      int col = col0 + wc * (BN / 2) + n * 16 + lr;
      float bc = bias[col];
      #pragma unroll
      for (int r = 0; r < 4; r++) {
        float v = acc[m][n][r] + bc;
        if (flags & 2) v = 0.5f * v * (1.f + erff(v * 0.70710678118f));
        size_t idx = (size_t)(row + r) * ldc + col;
        if (flags & 1) Cf[idx] += v;
        if (flags & 8) Cb[idx] = f2b(v);
      }
    }
  }
}

// ---------------- MFMA flash attention with relative positions ----------------
// Per block: 64 queries (4 waves x 16 rows), KV tiles of 64.
// score(l,j) = (q_l.k_j + q_l.Er[1023-l+j]) * 0.125, causal.
__global__ __launch_bounds__(256, 2) void attn_kernel(
    const u16* __restrict__ qkv,   // [4096,1536] bf16
    const u16* __restrict__ Erb,   // [1024,64] bf16 (this layer)
    u16* __restrict__ y) {         // [4096,512] bf16
  __shared__ u16 Qs[64 * 72];
  __shared__ u16 Ks[64 * 72];
  __shared__ u16 Vt[64 * 72];      // transposed: Vt[d][j]
  __shared__ u16 Es[128 * 72];
  __shared__ u16 Ps[64 * 72];
  const int qi = (int)gridDim.x - 1 - (int)blockIdx.x;  // heavy blocks first
  const int L0 = qi * 64;
  const int h = blockIdx.y, b = blockIdx.z;
  const int t = threadIdx.x, lane = t & 63, w = t >> 6;
  const int lr = lane & 15, lk = lane >> 4;
  const size_t base = (size_t)b * 1024 * 1536;

  #pragma unroll
  for (int r = 0; r < 2; r++) {
    int c = t + 256 * r;
    int qr = c >> 3, ko = c & 7;
    s16x8 v = *(const s16x8*)(qkv + base + (size_t)(L0 + qr) * 1536 + h * 64 + ko * 8);
    *(s16x8*)&Qs[qr * 72 + ko * 8] = v;
  }
  __syncthreads();
  const bf16x8 aq0 = *(const bf16x8*)&Qs[(w * 16 + lr) * 72 + lk * 8];
  const bf16x8 aq1 = *(const bf16x8*)&Qs[(w * 16 + lr) * 72 + lk * 8 + 32];

  f32x4 acc_o[4];
  float mrow[4], srow[4];
  #pragma unroll
  for (int n = 0; n < 4; n++) acc_o[n] = (f32x4){0.f, 0.f, 0.f, 0.f};
  #pragma unroll
  for (int r = 0; r < 4; r++) { mrow[r] = -INFINITY; srow[r] = 0.f; }

  const int lq0 = L0 + w * 16;
  const int ntiles = qi + 1;
  const f32x4 z4 = (f32x4){0.f, 0.f, 0.f, 0.f};

  for (int tt = 0; tt < ntiles; tt++) {
    const int j0 = tt * 64;
    __syncthreads();
    #pragma unroll
    for (int r = 0; r < 2; r++) {
      int c = t + 256 * r;
      int jr = c >> 3, ko = c & 7;
      s16x8 kv = *(const s16x8*)(qkv + base + (size_t)(j0 + jr) * 1536 + 512 + h * 64 + ko * 8);
      *(s16x8*)&Ks[jr * 72 + ko * 8] = kv;
      s16x8 vv = *(const s16x8*)(qkv + base + (size_t)(j0 + jr) * 1536 + 1024 + h * 64 + ko * 8);
      #pragma unroll
      for (int q = 0; q < 8; q++) Vt[(ko * 8 + q) * 72 + jr] = (u16)vv[q];
    }
    const int rb0 = 960 - L0 + j0;
    #pragma unroll
    for (int r = 0; r < 4; r++) {
      int c = t + 256 * r;
      int rr = c >> 3, ko = c & 7;
      int rb = rb0 + rr;
      s16x8 ev = {0, 0, 0, 0, 0, 0, 0, 0};
      if (rb < 1024) ev = *(const s16x8*)(Erb + (size_t)rb * 64 + ko * 8);
      *(s16x8*)&Es[rr * 72 + ko * 8] = ev;
    }
    __syncthreads();

    f32x4 sacc[4], gacc[5];
    #pragma unroll
    for (int n = 0; n < 4; n++) {
      bf16x8 b0 = *(const bf16x8*)&Ks[(n * 16 + lr) * 72 + lk * 8];
      bf16x8 b1 = *(const bf16x8*)&Ks[(n * 16 + lr) * 72 + lk * 8 + 32];
      sacc[n] = __builtin_amdgcn_mfma_f32_16x16x32_bf16(aq0, b0, z4, 0, 0, 0);
      sacc[n] = __builtin_amdgcn_mfma_f32_16x16x32_bf16(aq1, b1, sacc[n], 0, 0, 0);
    }
    #pragma unroll
    for (int g = 0; g < 5; g++) {
      int er = 48 - 16 * w + g * 16 + lr;
      bf16x8 b0 = *(const bf16x8*)&Es[er * 72 + lk * 8];
      bf16x8 b1 = *(const bf16x8*)&Es[er * 72 + lk * 8 + 32];
      gacc[g] = __builtin_amdgcn_mfma_f32_16x16x32_bf16(aq0, b0, z4, 0, 0, 0);
      gacc[g] = __builtin_amdgcn_mfma_f32_16x16x32_bf16(aq1, b1, gacc[g], 0, 0, 0);
    }

    const bool tile_masked = (j0 + 63 > lq0);
    float pv[4][4], corr[4];
    #pragma unroll
    for (int reg = 0; reg < 4; reg++) {
      int s = 15 - (lk * 4 + reg) + lr;          // in [0,30]
      int srcl = (lane & 48) | (s & 15);
      int gadd = s >> 4;
      float sh[5];
      #pragma unroll
      for (int g = 0; g < 5; g++) sh[g] = __shfl(gacc[g][reg], srcl, 64);
      int l_abs = lq0 + lk * 4 + reg;
      float sv[4];
      #pragma unroll
      for (int n = 0; n < 4; n++) {
        float gv = gadd ? sh[n + 1] : sh[n];
        float x = (sacc[n][reg] + gv) * 0.125f;
        int j_abs = j0 + n * 16 + lr;
        sv[n] = (tile_masked && j_abs > l_abs) ? -3.0e38f : x;
      }
      float mx = fmaxf(fmaxf(sv[0], sv[1]), fmaxf(sv[2], sv[3]));
      #pragma unroll
      for (int o = 1; o < 16; o <<= 1) mx = fmaxf(mx, __shfl_xor(mx, o, 64));
      float mnew = fmaxf(mrow[reg], mx);
      float cr = __expf(mrow[reg] - mnew);
      mrow[reg] = mnew;
      corr[reg] = cr;
      float ps = 0.f;
      #pragma unroll
      for (int n = 0; n < 4; n++) { float p = __expf(sv[n] - mnew); pv[reg][n] = p; ps += p; }
      #pragma unroll
      for (int o = 1; o < 16; o <<= 1) ps += __shfl_xor(ps, o, 64);
      srow[reg] = srow[reg] * cr + ps;
    }
    #pragma unroll
    for (int reg = 0; reg < 4; reg++) {
      int prow = w * 16 + lk * 4 + reg;
      #pragma unroll
      for (int n = 0; n < 4; n++) Ps[prow * 72 + n * 16 + lr] = f2b(pv[reg][n]);
    }
    #pragma unroll
    for (int n = 0; n < 4; n++) {
      f32x4 o = acc_o[n];
      #pragma unroll
      for (int reg = 0; reg < 4; reg++) o[reg] *= corr[reg];
      acc_o[n] = o;
    }
    bf16x8 ap0 = *(const bf16x8*)&Ps[(w * 16 + lr) * 72 + lk * 8];
    bf16x8 ap1 = *(const bf16x8*)&Ps[(w * 16 + lr) * 72 + lk * 8 + 32];
    #pragma unroll
    for (int n = 0; n < 4; n++) {
      bf16x8 b0 = *(const bf16x8*)&Vt[(n * 16 + lr) * 72 + lk * 8];
      bf16x8 b1 = *(const bf16x8*)&Vt[(n * 16 + lr) * 72 + lk * 8 + 32];
      acc_o[n] = __builtin_amdgcn_mfma_f32_16x16x32_bf16(ap0, b0, acc_o[n], 0, 0, 0);
      acc_o[n] = __builtin_amdgcn_mfma_f32_16x16x32_bf16(ap1, b1, acc_o[n], 0, 0, 0);
    }
  }
  #pragma unroll
  for (int reg = 0; reg < 4; reg++) {
    float inv = 1.0f / srow[reg];
    int row = b * 1024 + lq0 + lk * 4 + reg;
    #pragma unroll
    for (int n = 0; n < 4; n++)
      y[(size_t)row * 512 + h * 64 + n * 16 + lr] = f2b(acc_o[n][reg] * inv);
  }
}

// ---------------- extract heads region to output ----------------
__global__ void extract_kernel(const float* __restrict__ xcat, float* __restrict__ out) {
  int t = blockIdx.x;
  int c = threadIdx.x;
  if (c < 58) out[(size_t)t * 58 + c] = xcat[(size_t)t * 576 + 512 + c];
}

extern "C" void kernel_launch(void* const* d_in, const int* in_sizes, int n_in,
                              void* d_out, int out_size, void* d_ws, size_t ws_size,
                              hipStream_t stream) {
  const int* stage = (const int*)d_in[0];
  const int* egoc  = (const int*)d_in[1];
  const int* oppc  = (const int*)d_in[2];
  const int* egoa  = (const int*)d_in[3];
  const int* oppa  = (const int*)d_in[4];
  const float* gamestate  = (const float*)d_in[5];
  const float* controller = (const float*)d_in[6];
  const float* emb_stage  = (const float*)d_in[7];
  const float* emb_char   = (const float*)d_in[8];
  const float* emb_action = (const float*)d_in[9];
  const float* Wd = (const float*)d_in[10];
  const float* bd = (const float*)d_in[11];
  const float* ln1w = (const float*)d_in[12];
  const float* ln1b = (const float*)d_in[13];
  const float* Wqkv = (const float*)d_in[14];
  const float* bqkv = (const float*)d_in[15];
  const float* Wo = (const float*)d_in[16];
  const float* bo = (const float*)d_in[17];
  const float* Er = (const float*)d_in[18];
  const float* ln2w = (const float*)d_in[19];
  const float* ln2b = (const float*)d_in[20];
  const float* Wfc = (const float*)d_in[21];
  const float* bfc = (const float*)d_in[22];
  const float* Wp = (const float*)d_in[23];
  const float* bp = (const float*)d_in[24];
  const float* lnfw = (const float*)d_in[25];
  const float* lnfb = (const float*)d_in[26];

  char* wsb = (char*)d_ws;
  float* x    = (float*)(wsb + 0);             // [4096,512] f32
  float* xcat = (float*)(wsb + 8388608);       // [4096,576] f32
  u16* hb     = (u16*)(wsb + 17825792);        // [4096,512] bf16
  u16* qkvb   = (u16*)(wsb + 22020096);        // [4096,1536] bf16 (alias: xin, hln)
  u16* yb     = (u16*)(wsb + 34603008);        // [4096,512] bf16
  u16* ffb    = (u16*)(wsb + 38797312);        // [4096,2048] bf16 (alias: hh)
  u16* erb    = (u16*)(wsb + 55574528);        // [6,1024,64] bf16
  u16* wt1    = (u16*)(wsb + 56360960);        // [1536,512] bf16
  u16* wt2    = (u16*)(wsb + 57933824);        // [512,512]
  u16* wt3    = (u16*)(wsb + 58458112);        // [2048,512]
  u16* wt4    = (u16*)(wsb + 60555264);        // [512,2048]
  float* xin  = (float*)qkvb;                  // [4096,200] f32
  float* hln  = (float*)qkvb;                  // [4096,576] f32
  float* hh   = (float*)ffb;                   // [4096,288] f32
  float* out  = (float*)d_out;

  auto sgemm = [&](const float* A, int lda, const float* W, const float* bias,
                   float* C, int ldc, int N, int K, int flags) {
    dim3 g((N + 63) / 64, 32);
    sgemm_kernel<<<g, 256, 0, stream>>>(A, lda, W, bias, C, ldc, 4096, N, K, flags);
  };

  embed_kernel<<<4096, 256, 0, stream>>>(stage, egoc, oppc, egoa, oppa, gamestate,
                                         controller, emb_stage, emb_char, emb_action, xin);
  b16conv_kernel<<<1536, 256, 0, stream>>>(Er, erb, 6 * 1024 * 64);
  sgemm(xin, 200, Wd, bd, x, 512, 512, 200, 0);

  for (int i = 0; i < 6; i++) {
    ln_kernel<u16><<<1024, 256, 0, stream>>>(x, 512, hb, 512, ln1w + i * 512, ln1b + i * 512, 512);
    tpose_kernel<<<dim3(48, 16), 256, 0, stream>>>(Wqkv + (size_t)i * 512 * 1536, wt1, 512, 1536);
    mgemm_kernel<128><<<dim3(12, 32), 256, 0, stream>>>(hb, wt1, bqkv + i * 1536,
                                                        nullptr, qkvb, 512, 1536, 8);
    attn_kernel<<<dim3(16, 8, 4), 256, 0, stream>>>(qkvb, erb + (size_t)i * 1024 * 64, yb);
    tpose_kernel<<<dim3(16, 16), 256, 0, stream>>>(Wo + (size_t)i * 512 * 512, wt2, 512, 512);
    mgemm_kernel<64><<<dim3(8, 32), 256, 0, stream>>>(yb, wt2, bo + i * 512,
                                                      x, nullptr, 512, 512, 1);
    ln_kernel<u16><<<1024, 256, 0, stream>>>(x, 512, hb, 512, ln2w + i * 512, ln2b + i * 512, 512);
    tpose_kernel<<<dim3(64, 16), 256, 0, stream>>>(Wfc + (size_t)i * 512 * 2048, wt3, 512, 2048);
    mgemm_kernel<128><<<dim3(16, 32), 256, 0, stream>>>(hb, wt3, bfc + i * 2048,
                                                        nullptr, ffb, 512, 2048, 2 | 8);
    tpose_kernel<<<dim3(16, 64), 256, 0, stream>>>(Wp + (size_t)i * 2048 * 512, wt4, 2048, 512);
    mgemm_kernel<64><<<dim3(8, 32), 256, 0, stream>>>(ffb, wt4, bp + i * 512,
                                                      x, nullptr, 2048, 512, 1);
  }

  ln_kernel<float><<<1024, 256, 0, stream>>>(x, 512, xcat, 576, lnfw, lnfb, 512);

  const float* hp[24];
  for (int k = 0; k < 24; k++) hp[k] = (const float*)d_in[27 + k];
  const int din[4]  = {512, 533, 554, 566};
  const int dh[4]   = {256, 266, 277, 283};
  const int dout[4] = {21, 21, 12, 4};
  int col = 512;
  for (int hd = 0; hd < 4; hd++) {
    const float* lw = hp[hd * 6 + 0];
    const float* lb = hp[hd * 6 + 1];
    const float* W1 = hp[hd * 6 + 2];
    const float* b1 = hp[hd * 6 + 3];
    const float* W2 = hp[hd * 6 + 4];
    const float* b2 = hp[hd * 6 + 5];
    ln_kernel<float><<<1024, 256, 0, stream>>>(xcat, 576, hln, 576, lw, lb, din[hd]);
    sgemm(hln, 576, W1, b1, hh, 288, dh[hd], din[hd], 2);
    sgemm(hh, 288, W2, b2, xcat + col, 576, dout[hd], dh[hd], 0);
    col += dout[hd];
  }

  extract_kernel<<<4096, 64, 0, stream>>>(xcat, out);
}

// Round 3
// 1609.987 us; speedup vs baseline: 5.9192x; 1.3578x over previous
//
#include <hip/hip_runtime.h>
#include <math.h>

typedef unsigned short u16;
typedef __bf16 bf16x8 __attribute__((ext_vector_type(8)));
typedef short s16x8 __attribute__((ext_vector_type(8)));
typedef float f32x4 __attribute__((ext_vector_type(4)));

__device__ __forceinline__ u16 f2b(float f) {
  union { float f; unsigned u; } x; x.f = f;
  unsigned r = x.u + 0x7fff + ((x.u >> 16) & 1);
  return (u16)(r >> 16);
}

__device__ __forceinline__ void gload16(const void* g, void* l) {
  __builtin_amdgcn_global_load_lds((const __attribute__((address_space(1))) unsigned int*)g,
                                   (__attribute__((address_space(3))) unsigned int*)l, 16, 0, 0);
}

// ---------------- embedding concat -> bf16, zero-padded to 224 cols ----------------
__global__ void embed_kernel(const int* __restrict__ stage, const int* __restrict__ egoc,
                             const int* __restrict__ oppc, const int* __restrict__ egoa,
                             const int* __restrict__ oppa,
                             const float* __restrict__ gamestate, const float* __restrict__ controller,
                             const float* __restrict__ emb_stage, const float* __restrict__ emb_char,
                             const float* __restrict__ emb_action,
                             u16* __restrict__ xinb) {
  int t = blockIdx.x;
  int c = threadIdx.x;
  if (c >= 224) return;
  float v = 0.f;
  if (c < 8)        v = emb_stage[stage[t] * 8 + c];
  else if (c < 24)  v = emb_char[egoc[t] * 16 + (c - 8)];
  else if (c < 40)  v = emb_char[oppc[t] * 16 + (c - 24)];
  else if (c < 72)  v = emb_action[egoa[t] * 32 + (c - 40)];
  else if (c < 104) v = emb_action[oppa[t] * 32 + (c - 72)];
  else if (c < 168) v = gamestate[t * 64 + (c - 104)];
  else if (c < 200) v = controller[t * 32 + (c - 168)];
  xinb[t * 224 + c] = f2b(v);
}

// ---------------- layernorm (one wave per row); T = float or u16(bf16) ----------------
// writes zeros for cols [d, dpad)
template<typename T>
__global__ void ln_kernel(const float* __restrict__ in, int ldi,
                          T* __restrict__ out, int ldo,
                          const float* __restrict__ w, const float* __restrict__ b,
                          int d, int dpad) {
  int wid = threadIdx.x >> 6;
  int lane = threadIdx.x & 63;
  int row = blockIdx.x * 4 + wid;
  const float* ip = in + (size_t)row * ldi;
  float v[9];
  int n = 0;
  float s = 0.f;
  for (int c = lane; c < d; c += 64) { v[n] = ip[c]; s += v[n]; n++; }
  #pragma unroll
  for (int o = 32; o; o >>= 1) s += __shfl_xor(s, o);
  float mu = s / (float)d;
  float q = 0.f;
  for (int i = 0; i < n; i++) { float t = v[i] - mu; q += t * t; }
  #pragma unroll
  for (int o = 32; o; o >>= 1) q += __shfl_xor(q, o);
  float rstd = rsqrtf(q / (float)d + 1e-5f);
  T* op = out + (size_t)row * ldo;
  int c = lane;
  for (int i = 0; i < n; i++, c += 64) {
    float val = (v[i] - mu) * rstd * w[c] + b[c];
    if constexpr (sizeof(T) == 2) op[c] = f2b(val); else op[c] = val;
  }
  for (int cz = (d & ~63) + lane; cz < dpad; cz += 64)
    if (cz >= d) { if constexpr (sizeof(T) == 2) op[cz] = 0; else op[cz] = 0.f; }
}

// ---------------- multi-job weight transpose+convert: in[K,N] f32 -> out[Nout,Kout] bf16 ----
// zero-fills pad rows/cols.
struct TJob { const float* src; u16* dst; int K, N, Kout, Nout, start; };
struct TJobs { TJob j[12]; int njobs; };

__global__ void multi_tpose(TJobs jobs) {
  int bid = blockIdx.x;
  int ji = 0;
  while (ji + 1 < jobs.njobs && bid >= jobs.j[ji + 1].start) ji++;
  TJob jb = jobs.j[ji];
  int local = bid - jb.start;
  int ntx = jb.Nout >> 5;
  int n0 = (local % ntx) << 5;
  int k0 = (local / ntx) << 5;
  __shared__ float tile[32][33];
  int tx = threadIdx.x & 31, ty = threadIdx.x >> 5;
  #pragma unroll
  for (int q = 0; q < 4; q++) {
    int k = k0 + ty + q * 8, n = n0 + tx;
    tile[ty + q * 8][tx] = (k < jb.K && n < jb.N) ? jb.src[(size_t)k * jb.N + n] : 0.f;
  }
  __syncthreads();
  #pragma unroll
  for (int q = 0; q < 4; q++)
    jb.dst[(size_t)(n0 + ty + q * 8) * jb.Kout + k0 + tx] = f2b(tile[tx][ty + q * 8]);
}

__global__ void b16conv_kernel(const float* __restrict__ in, u16* __restrict__ out, int n) {
  int i = blockIdx.x * 256 + threadIdx.x;
  if (i < n) out[i] = f2b(in[i]);
}

// ---------------- pad head biases ----------------
struct PBias { const float* b1[4]; const float* b2[4]; int dh[4]; int dout[4]; };
__global__ void pad_bias_kernel(PBias pb, float* __restrict__ b1p, float* __restrict__ b2p) {
  int t = threadIdx.x;
  for (int hd = 0; hd < 4; hd++) {
    for (int c = t; c < 288; c += 256) b1p[hd * 288 + c] = (c < pb.dh[hd]) ? pb.b1[hd][c] : 0.f;
    for (int c = t; c < 64; c += 256)  b2p[hd * 64 + c] = (c < pb.dout[hd]) ? pb.b2[hd][c] : 0.f;
  }
}

// ---------------- bf16 MFMA GEMM: C = act(A[M,K] @ Bt[N,K]^T + bias) ----------------
// BM=128, BK=32, 256 threads, 4 waves (2x2), wave tile 64 x (BN/2).
// flags: 1 = Cf += v, 2 = gelu, 4 = Cf = v, 8 = Cb(bf16) = v. Writes only col < Nreal.
template<int BN>
__global__ __launch_bounds__(256, 2) void mgemm_kernel(
    const u16* __restrict__ A, const u16* __restrict__ Bt, const float* __restrict__ bias,
    float* __restrict__ Cf, u16* __restrict__ Cb, int K, int ldc, int flags, int Nreal) {
  constexpr int NR = BN / 32;          // 16-col fragments per wave
  __shared__ u16 As[2][128 * 32];
  __shared__ u16 Bs[2][BN * 32];
  const int t = threadIdx.x;
  const int row0 = blockIdx.y * 128;
  const int col0 = blockIdx.x * BN;
  const int lane = t & 63, wv = t >> 6;
  const int wr = wv >> 1, wc = wv & 1;
  const int lr = lane & 15, lk = lane >> 4;

  f32x4 acc[4][NR];
  #pragma unroll
  for (int m = 0; m < 4; m++)
    #pragma unroll
    for (int n = 0; n < NR; n++) acc[m][n] = (f32x4){0.f, 0.f, 0.f, 0.f};

  auto stage = [&](int buf, int kt) {
    #pragma unroll
    for (int r = 0; r < 2; r++) {
      int c = t + 256 * r;
      gload16(A + (size_t)(row0 + (c >> 2)) * K + kt + (c & 3) * 8, &As[buf][c * 8]);
    }
    for (int c = t; c < BN * 4; c += 256)
      gload16(Bt + (size_t)(col0 + (c >> 2)) * K + kt + (c & 3) * 8, &Bs[buf][c * 8]);
  };

  stage(0, 0);
  const int nt = K >> 5;
  const int abase = (wr * 64 + lr) * 32 + lk * 8;
  const int bbase = (wc * (BN / 2) + lr) * 32 + lk * 8;
  for (int tile = 0; tile < nt; tile++) {
    __syncthreads();
    int cur = tile & 1;
    if (tile + 1 < nt) stage(cur ^ 1, (tile + 1) * 32);
    bf16x8 af[4], bfr[NR];
    #pragma unroll
    for (int m = 0; m < 4; m++) af[m] = *(const bf16x8*)&As[cur][abase + m * 16 * 32];
    #pragma unroll
    for (int n = 0; n < NR; n++) bfr[n] = *(const bf16x8*)&Bs[cur][bbase + n * 16 * 32];
    #pragma unroll
    for (int m = 0; m < 4; m++)
      #pragma unroll
      for (int n = 0; n < NR; n++)
        acc[m][n] = __builtin_amdgcn_mfma_f32_16x16x32_bf16(af[m], bfr[n], acc[m][n], 0, 0, 0);
  }
  #pragma unroll
  for (int m = 0; m < 4; m++) {
    int row = row0 + wr * 64 + m * 16 + lk * 4;
    #pragma unroll
    for (int n = 0; n < NR; n++) {
      int col = col0 + wc * (BN / 2) + n * 16 + lr;
      if (col >= Nreal) continue;
      float bc = bias[col];
      #pragma unroll
      for (int r = 0; r < 4; r++) {
        float v = acc[m][n][r] + bc;
        if (flags & 2) v = 0.5f * v * (1.f + erff(v * 0.70710678118f));
        size_t idx = (size_t)(row + r) * ldc + col;
        if (flags & 1) Cf[idx] += v;
        if (flags & 4) Cf[idx] = v;
        if (flags & 8) Cb[idx] = f2b(v);
      }
    }
  }
}

// ---------------- MFMA flash attention with relative positions ----------------
__global__ __launch_bounds__(256, 2) void attn_kernel(
    const u16* __restrict__ qkv,   // [4096,1536] bf16
    const u16* __restrict__ Erb,   // [1024,64] bf16 (this layer)
    u16* __restrict__ y) {         // [4096,512] bf16
  __shared__ u16 Qs[64 * 72];
  __shared__ u16 Ks[64 * 72];
  __shared__ u16 Vt[64 * 72];      // transposed: Vt[d][j]
  __shared__ u16 Es[128 * 72];
  __shared__ u16 Ps[64 * 72];
  const int qi = (int)gridDim.x - 1 - (int)blockIdx.x;  // heavy blocks first
  const int L0 = qi * 64;
  const int h = blockIdx.y, b = blockIdx.z;
  const int t = threadIdx.x, lane = t & 63, w = t >> 6;
  const int lr = lane & 15, lk = lane >> 4;
  const size_t base = (size_t)b * 1024 * 1536;

  #pragma unroll
  for (int r = 0; r < 2; r++) {
    int c = t + 256 * r;
    int qr = c >> 3, ko = c & 7;
    s16x8 v = *(const s16x8*)(qkv + base + (size_t)(L0 + qr) * 1536 + h * 64 + ko * 8);
    *(s16x8*)&Qs[qr * 72 + ko * 8] = v;
  }
  __syncthreads();
  const bf16x8 aq0 = *(const bf16x8*)&Qs[(w * 16 + lr) * 72 + lk * 8];
  const bf16x8 aq1 = *(const bf16x8*)&Qs[(w * 16 + lr) * 72 + lk * 8 + 32];

  f32x4 acc_o[4];
  float mrow[4], srow[4];
  #pragma unroll
  for (int n = 0; n < 4; n++) acc_o[n] = (f32x4){0.f, 0.f, 0.f, 0.f};
  #pragma unroll
  for (int r = 0; r < 4; r++) { mrow[r] = -INFINITY; srow[r] = 0.f; }

  const int lq0 = L0 + w * 16;
  const int ntiles = qi + 1;
  const f32x4 z4 = (f32x4){0.f, 0.f, 0.f, 0.f};

  for (int tt = 0; tt < ntiles; tt++) {
    const int j0 = tt * 64;
    __syncthreads();
    #pragma unroll
    for (int r = 0; r < 2; r++) {
      int c = t + 256 * r;
      int jr = c >> 3, ko = c & 7;
      s16x8 kv = *(const s16x8*)(qkv + base + (size_t)(j0 + jr) * 1536 + 512 + h * 64 + ko * 8);
      *(s16x8*)&Ks[jr * 72 + ko * 8] = kv;
      s16x8 vv = *(const s16x8*)(qkv + base + (size_t)(j0 + jr) * 1536 + 1024 + h * 64 + ko * 8);
      #pragma unroll
      for (int q = 0; q < 8; q++) Vt[(ko * 8 + q) * 72 + jr] = (u16)vv[q];
    }
    const int rb0 = 960 - L0 + j0;
    #pragma unroll
    for (int r = 0; r < 4; r++) {
      int c = t + 256 * r;
      int rr = c >> 3, ko = c & 7;
      int rb = rb0 + rr;
      s16x8 ev = {0, 0, 0, 0, 0, 0, 0, 0};
      if (rb < 1024) ev = *(const s16x8*)(Erb + (size_t)rb * 64 + ko * 8);
      *(s16x8*)&Es[rr * 72 + ko * 8] = ev;
    }
    __syncthreads();

    f32x4 sacc[4], gacc[5];
    #pragma unroll
    for (int n = 0; n < 4; n++) {
      bf16x8 b0 = *(const bf16x8*)&Ks[(n * 16 + lr) * 72 + lk * 8];
      bf16x8 b1 = *(const bf16x8*)&Ks[(n * 16 + lr) * 72 + lk * 8 + 32];
      sacc[n] = __builtin_amdgcn_mfma_f32_16x16x32_bf16(aq0, b0, z4, 0, 0, 0);
      sacc[n] = __builtin_amdgcn_mfma_f32_16x16x32_bf16(aq1, b1, sacc[n], 0, 0, 0);
    }
    #pragma unroll
    for (int g = 0; g < 5; g++) {
      int er = 48 - 16 * w + g * 16 + lr;
      bf16x8 b0 = *(const bf16x8*)&Es[er * 72 + lk * 8];
      bf16x8 b1 = *(const bf16x8*)&Es[er * 72 + lk * 8 + 32];
      gacc[g] = __builtin_amdgcn_mfma_f32_16x16x32_bf16(aq0, b0, z4, 0, 0, 0);
      gacc[g] = __builtin_amdgcn_mfma_f32_16x16x32_bf16(aq1, b1, gacc[g], 0, 0, 0);
    }

    const bool tile_masked = (j0 + 63 > lq0);
    float pv[4][4], corr[4];
    #pragma unroll
    for (int reg = 0; reg < 4; reg++) {
      int s = 15 - (lk * 4 + reg) + lr;          // in [0,30]
      int srcl = (lane & 48) | (s & 15);
      int gadd = s >> 4;
      float sh[5];
      #pragma unroll
      for (int g = 0; g < 5; g++) sh[g] = __shfl(gacc[g][reg], srcl, 64);
      int l_abs = lq0 + lk * 4 + reg;
      float sv[4];
      #pragma unroll
      for (int n = 0; n < 4; n++) {
        float gv = gadd ? sh[n + 1] : sh[n];
        float x = (sacc[n][reg] + gv) * 0.125f;
        int j_abs = j0 + n * 16 + lr;
        sv[n] = (tile_masked && j_abs > l_abs) ? -3.0e38f : x;
      }
      float mx = fmaxf(fmaxf(sv[0], sv[1]), fmaxf(sv[2], sv[3]));
      #pragma unroll
      for (int o = 1; o < 16; o <<= 1) mx = fmaxf(mx, __shfl_xor(mx, o, 64));
      float mnew = fmaxf(mrow[reg], mx);
      float cr = __expf(mrow[reg] - mnew);
      mrow[reg] = mnew;
      corr[reg] = cr;
      float ps = 0.f;
      #pragma unroll
      for (int n = 0; n < 4; n++) { float p = __expf(sv[n] - mnew); pv[reg][n] = p; ps += p; }
      #pragma unroll
      for (int o = 1; o < 16; o <<= 1) ps += __shfl_xor(ps, o, 64);
      srow[reg] = srow[reg] * cr + ps;
    }
    #pragma unroll
    for (int reg = 0; reg < 4; reg++) {
      int prow = w * 16 + lk * 4 + reg;
      #pragma unroll
      for (int n = 0; n < 4; n++) Ps[prow * 72 + n * 16 + lr] = f2b(pv[reg][n]);
    }
    #pragma unroll
    for (int n = 0; n < 4; n++) {
      f32x4 o = acc_o[n];
      #pragma unroll
      for (int reg = 0; reg < 4; reg++) o[reg] *= corr[reg];
      acc_o[n] = o;
    }
    bf16x8 ap0 = *(const bf16x8*)&Ps[(w * 16 + lr) * 72 + lk * 8];
    bf16x8 ap1 = *(const bf16x8*)&Ps[(w * 16 + lr) * 72 + lk * 8 + 32];
    #pragma unroll
    for (int n = 0; n < 4; n++) {
      bf16x8 b0 = *(const bf16x8*)&Vt[(n * 16 + lr) * 72 + lk * 8];
      bf16x8 b1 = *(const bf16x8*)&Vt[(n * 16 + lr) * 72 + lk * 8 + 32];
      acc_o[n] = __builtin_amdgcn_mfma_f32_16x16x32_bf16(ap0, b0, acc_o[n], 0, 0, 0);
      acc_o[n] = __builtin_amdgcn_mfma_f32_16x16x32_bf16(ap1, b1, acc_o[n], 0, 0, 0);
    }
  }
  #pragma unroll
  for (int reg = 0; reg < 4; reg++) {
    float inv = 1.0f / srow[reg];
    int row = b * 1024 + lq0 + lk * 4 + reg;
    #pragma unroll
    for (int n = 0; n < 4; n++)
      y[(size_t)row * 512 + h * 64 + n * 16 + lr] = f2b(acc_o[n][reg] * inv);
  }
}

// ---------------- extract heads region to output ----------------
__global__ void extract_kernel(const float* __restrict__ xcat, float* __restrict__ out) {
  int t = blockIdx.x;
  int c = threadIdx.x;
  if (c < 58) out[(size_t)t * 58 + c] = xcat[(size_t)t * 576 + 512 + c];
}

extern "C" void kernel_launch(void* const* d_in, const int* in_sizes, int n_in,
                              void* d_out, int out_size, void* d_ws, size_t ws_size,
                              hipStream_t stream) {
  const int* stage = (const int*)d_in[0];
  const int* egoc  = (const int*)d_in[1];
  const int* oppc  = (const int*)d_in[2];
  const int* egoa  = (const int*)d_in[3];
  const int* oppa  = (const int*)d_in[4];
  const float* gamestate  = (const float*)d_in[5];
  const float* controller = (const float*)d_in[6];
  const float* emb_stage  = (const float*)d_in[7];
  const float* emb_char   = (const float*)d_in[8];
  const float* emb_action = (const float*)d_in[9];
  const float* Wd = (const float*)d_in[10];
  const float* bd = (const float*)d_in[11];
  const float* ln1w = (const float*)d_in[12];
  const float* ln1b = (const float*)d_in[13];
  const float* Wqkv = (const float*)d_in[14];
  const float* bqkv = (const float*)d_in[15];
  const float* Wo = (const float*)d_in[16];
  const float* bo = (const float*)d_in[17];
  const float* Er = (const float*)d_in[18];
  const float* ln2w = (const float*)d_in[19];
  const float* ln2b = (const float*)d_in[20];
  const float* Wfc = (const float*)d_in[21];
  const float* bfc = (const float*)d_in[22];
  const float* Wp = (const float*)d_in[23];
  const float* bp = (const float*)d_in[24];
  const float* lnfw = (const float*)d_in[25];
  const float* lnfb = (const float*)d_in[26];

  char* wsb = (char*)d_ws;
  float* x    = (float*)(wsb + 0);             // [4096,512] f32
  float* xcat = (float*)(wsb + 8388608);       // [4096,576] f32
  u16* hb     = (u16*)(wsb + 17825792);        // [4096,512] bf16
  u16* qkvb   = (u16*)(wsb + 22020096);        // [4096,1536] bf16 (alias: hlnb)
  u16* yb     = (u16*)(wsb + 34603008);        // [4096,512] bf16 (alias: hhb)
  u16* ffb    = (u16*)(wsb + 38797312);        // [4096,2048] bf16 (alias: xinb)
  u16* erb    = (u16*)(wsb + 55574528);        // [6,1024,64] bf16
  u16* wt1    = (u16*)(wsb + 56360960);        // [1536,512]
  u16* wt2    = (u16*)(wsb + 57933824);        // [512,512]
  u16* wt3    = (u16*)(wsb + 58458112);        // [2048,512]
  u16* wt4    = (u16*)(wsb + 60555264);        // [512,2048]
  u16* wdt    = (u16*)(wsb + 62652416);        // [512,224]
  u16* w1t    = (u16*)(wsb + 62881792);        // 4 x [288,576]
  u16* w2t    = (u16*)(wsb + 64208896);        // 4 x [64,288]
  float* b1p  = (float*)(wsb + 64356352);      // 4 x 288
  float* b2p  = (float*)(wsb + 64360960);      // 4 x 64
  u16* xinb   = ffb;                           // [4096,224] bf16
  u16* hlnb   = qkvb;                          // [4096,576] bf16
  u16* hhb    = yb;                            // [4096,288] bf16
  float* out  = (float*)d_out;

  const float* hp[24];
  for (int k = 0; k < 24; k++) hp[k] = (const float*)d_in[27 + k];
  const int din[4]  = {512, 533, 554, 566};
  const int dh[4]   = {256, 266, 277, 283};
  const int dout[4] = {21, 21, 12, 4};

  auto addJob = [](TJobs& J, const float* src, u16* dst, int K, int N, int Kout, int Nout) {
    int i = J.njobs;
    J.j[i].src = src; J.j[i].dst = dst;
    J.j[i].K = K; J.j[i].N = N; J.j[i].Kout = Kout; J.j[i].Nout = Nout;
    J.j[i].start = (i == 0) ? 0
                 : J.j[i - 1].start + (J.j[i - 1].Nout >> 5) * (J.j[i - 1].Kout >> 5);
    J.njobs = i + 1;
  };
  auto jblocks = [](const TJobs& J) {
    const TJob& l = J.j[J.njobs - 1];
    return l.start + (l.Nout >> 5) * (l.Kout >> 5);
  };

  // ---- prep: embed, Er conv, misc transposes, bias pads, embed proj ----
  embed_kernel<<<4096, 256, 0, stream>>>(stage, egoc, oppc, egoa, oppa, gamestate,
                                         controller, emb_stage, emb_char, emb_action, xinb);
  b16conv_kernel<<<1536, 256, 0, stream>>>(Er, erb, 6 * 1024 * 64);
  {
    TJobs J; J.njobs = 0;
    addJob(J, Wd, wdt, 200, 512, 224, 512);
    for (int hd = 0; hd < 4; hd++)
      addJob(J, hp[hd * 6 + 2], w1t + hd * 288 * 576, din[hd], dh[hd], 576, 288);
    for (int hd = 0; hd < 4; hd++)
      addJob(J, hp[hd * 6 + 4], w2t + hd * 64 * 288, dh[hd], dout[hd], 288, 64);
    multi_tpose<<<jblocks(J), 256, 0, stream>>>(J);
  }
  {
    PBias pb;
    for (int hd = 0; hd < 4; hd++) {
      pb.b1[hd] = hp[hd * 6 + 3]; pb.b2[hd] = hp[hd * 6 + 5];
      pb.dh[hd] = dh[hd]; pb.dout[hd] = dout[hd];
    }
    pad_bias_kernel<<<1, 256, 0, stream>>>(pb, b1p, b2p);
  }
  mgemm_kernel<128><<<dim3(4, 32), 256, 0, stream>>>(xinb, wdt, bd, x, nullptr, 224, 512, 4, 1 << 30);

  // ---- transformer layers ----
  for (int i = 0; i < 6; i++) {
    {
      TJobs J; J.njobs = 0;
      addJob(J, Wqkv + (size_t)i * 512 * 1536, wt1, 512, 1536, 512, 1536);
      addJob(J, Wo + (size_t)i * 512 * 512, wt2, 512, 512, 512, 512);
      addJob(J, Wfc + (size_t)i * 512 * 2048, wt3, 512, 2048, 512, 2048);
      addJob(J, Wp + (size_t)i * 2048 * 512, wt4, 2048, 512, 2048, 512);
      multi_tpose<<<jblocks(J), 256, 0, stream>>>(J);
    }
    ln_kernel<u16><<<1024, 256, 0, stream>>>(x, 512, hb, 512, ln1w + i * 512, ln1b + i * 512, 512, 512);
    mgemm_kernel<128><<<dim3(12, 32), 256, 0, stream>>>(hb, wt1, bqkv + i * 1536,
                                                        nullptr, qkvb, 512, 1536, 8, 1 << 30);
    attn_kernel<<<dim3(16, 8, 4), 256, 0, stream>>>(qkvb, erb + (size_t)i * 1024 * 64, yb);
    mgemm_kernel<64><<<dim3(8, 32), 256, 0, stream>>>(yb, wt2, bo + i * 512,
                                                      x, nullptr, 512, 512, 1, 1 << 30);
    ln_kernel<u16><<<1024, 256, 0, stream>>>(x, 512, hb, 512, ln2w + i * 512, ln2b + i * 512, 512, 512);
    mgemm_kernel<128><<<dim3(16, 32), 256, 0, stream>>>(hb, wt3, bfc + i * 2048,
                                                        nullptr, ffb, 512, 2048, 2 | 8, 1 << 30);
    mgemm_kernel<64><<<dim3(8, 32), 256, 0, stream>>>(ffb, wt4, bp + i * 512,
                                                      x, nullptr, 2048, 512, 1, 1 << 30);
  }

  // ---- final LN + heads (all MFMA) ----
  ln_kernel<float><<<1024, 256, 0, stream>>>(x, 512, xcat, 576, lnfw, lnfb, 512, 512);
  int col = 512;
  for (int hd = 0; hd < 4; hd++) {
    ln_kernel<u16><<<1024, 256, 0, stream>>>(xcat, 576, hlnb, 576,
                                             hp[hd * 6 + 0], hp[hd * 6 + 1], din[hd], 576);
    mgemm_kernel<96><<<dim3(3, 32), 256, 0, stream>>>(hlnb, w1t + hd * 288 * 576, b1p + hd * 288,
                                                      nullptr, hhb, 576, 288, 2 | 8, 1 << 30);
    mgemm_kernel<64><<<dim3(1, 32), 256, 0, stream>>>(hhb, w2t + hd * 64 * 288, b2p + hd * 64,
                                                      xcat + col, nullptr, 288, 576, 4, dout[hd]);
    col += dout[hd];
  }

  extract_kernel<<<4096, 64, 0, stream>>>(xcat, out);
}

// Round 5
// 1515.410 us; speedup vs baseline: 6.2886x; 1.0624x over previous
//
#include <hip/hip_runtime.h>
#include <math.h>

typedef unsigned short u16;
typedef __bf16 bf16x8 __attribute__((ext_vector_type(8)));
typedef short s16x8 __attribute__((ext_vector_type(8)));
typedef short s16x4 __attribute__((ext_vector_type(4)));
typedef float f32x4 __attribute__((ext_vector_type(4)));

__device__ __forceinline__ u16 f2b(float f) {
  union { float f; unsigned u; } x; x.f = f;
  unsigned r = x.u + 0x7fff + ((x.u >> 16) & 1);
  return (u16)(r >> 16);
}

__device__ __forceinline__ void gload16(const void* g, void* l) {
  __builtin_amdgcn_global_load_lds((const __attribute__((address_space(1))) unsigned int*)g,
                                   (__attribute__((address_space(3))) unsigned int*)l, 16, 0, 0);
}

// ---------------- embedding concat -> bf16, zero-padded to 224 cols ----------------
__global__ void embed_kernel(const int* __restrict__ stage, const int* __restrict__ egoc,
                             const int* __restrict__ oppc, const int* __restrict__ egoa,
                             const int* __restrict__ oppa,
                             const float* __restrict__ gamestate, const float* __restrict__ controller,
                             const float* __restrict__ emb_stage, const float* __restrict__ emb_char,
                             const float* __restrict__ emb_action,
                             u16* __restrict__ xinb) {
  int t = blockIdx.x;
  int c = threadIdx.x;
  if (c >= 224) return;
  float v = 0.f;
  if (c < 8)        v = emb_stage[stage[t] * 8 + c];
  else if (c < 24)  v = emb_char[egoc[t] * 16 + (c - 8)];
  else if (c < 40)  v = emb_char[oppc[t] * 16 + (c - 24)];
  else if (c < 72)  v = emb_action[egoa[t] * 32 + (c - 40)];
  else if (c < 104) v = emb_action[oppa[t] * 32 + (c - 72)];
  else if (c < 168) v = gamestate[t * 64 + (c - 104)];
  else if (c < 200) v = controller[t * 32 + (c - 168)];
  xinb[t * 224 + c] = f2b(v);
}

// ---------------- generic layernorm (one wave per row); T = float or u16 ----------------
template<typename T>
__global__ void ln_kernel(const float* __restrict__ in, int ldi,
                          T* __restrict__ out, int ldo,
                          const float* __restrict__ w, const float* __restrict__ b,
                          int d, int dpad) {
  int wid = threadIdx.x >> 6;
  int lane = threadIdx.x & 63;
  int row = blockIdx.x * 4 + wid;
  const float* ip = in + (size_t)row * ldi;
  float v[9];
  int n = 0;
  float s = 0.f;
  for (int c = lane; c < d; c += 64) { v[n] = ip[c]; s += v[n]; n++; }
  #pragma unroll
  for (int o = 32; o; o >>= 1) s += __shfl_xor(s, o);
  float mu = s / (float)d;
  float q = 0.f;
  for (int i = 0; i < n; i++) { float t = v[i] - mu; q += t * t; }
  #pragma unroll
  for (int o = 32; o; o >>= 1) q += __shfl_xor(q, o);
  float rstd = rsqrtf(q / (float)d + 1e-5f);
  T* op = out + (size_t)row * ldo;
  int c = lane;
  for (int i = 0; i < n; i++, c += 64) {
    float val = (v[i] - mu) * rstd * w[c] + b[c];
    if constexpr (sizeof(T) == 2) op[c] = f2b(val); else op[c] = val;
  }
  for (int cz = (d & ~63) + lane; cz < dpad; cz += 64)
    if (cz >= d) { if constexpr (sizeof(T) == 2) op[cz] = 0; else op[cz] = 0.f; }
}

// ---------------- vectorized LN for d=512, f32 in -> bf16 out (ld 512) ----------------
__global__ void ln512_kernel(const float* __restrict__ in, u16* __restrict__ out,
                             const float* __restrict__ w, const float* __restrict__ b) {
  int wid = threadIdx.x >> 6, lane = threadIdx.x & 63;
  int row = blockIdx.x * 4 + wid;
  const float4* ip = (const float4*)(in + (size_t)row * 512);
  float4 x0 = ip[lane], x1 = ip[lane + 64];
  float s = x0.x + x0.y + x0.z + x0.w + x1.x + x1.y + x1.z + x1.w;
  #pragma unroll
  for (int o = 32; o; o >>= 1) s += __shfl_xor(s, o);
  float mu = s * (1.f / 512.f);
  float q = (x0.x-mu)*(x0.x-mu) + (x0.y-mu)*(x0.y-mu) + (x0.z-mu)*(x0.z-mu) + (x0.w-mu)*(x0.w-mu)
          + (x1.x-mu)*(x1.x-mu) + (x1.y-mu)*(x1.y-mu) + (x1.z-mu)*(x1.z-mu) + (x1.w-mu)*(x1.w-mu);
  #pragma unroll
  for (int o = 32; o; o >>= 1) q += __shfl_xor(q, o);
  float rstd = rsqrtf(q * (1.f / 512.f) + 1e-5f);
  const float4* w4 = (const float4*)w;
  const float4* b4 = (const float4*)b;
  float4 w0 = w4[lane], w1 = w4[lane + 64], c0 = b4[lane], c1 = b4[lane + 64];
  ushort4 o0, o1;
  o0.x = f2b((x0.x - mu) * rstd * w0.x + c0.x);
  o0.y = f2b((x0.y - mu) * rstd * w0.y + c0.y);
  o0.z = f2b((x0.z - mu) * rstd * w0.z + c0.z);
  o0.w = f2b((x0.w - mu) * rstd * w0.w + c0.w);
  o1.x = f2b((x1.x - mu) * rstd * w1.x + c1.x);
  o1.y = f2b((x1.y - mu) * rstd * w1.y + c1.y);
  o1.z = f2b((x1.z - mu) * rstd * w1.z + c1.z);
  o1.w = f2b((x1.w - mu) * rstd * w1.w + c1.w);
  *(ushort4*)(out + (size_t)row * 512 + lane * 4) = o0;
  *(ushort4*)(out + (size_t)row * 512 + 256 + lane * 4) = o1;
}

// ---------------- multi-job weight transpose+convert: in[K,N] f32 -> out[Nout,Kout] bf16 ----
struct TJob { const float* src; u16* dst; int K, N, Kout, Nout, start; };
struct TJobs { TJob j[26]; int njobs; };

__global__ void multi_tpose(TJobs jobs) {
  int bid = blockIdx.x;
  int ji = 0;
  while (ji + 1 < jobs.njobs && bid >= jobs.j[ji + 1].start) ji++;
  TJob jb = jobs.j[ji];
  int local = bid - jb.start;
  int ntx = jb.Nout >> 5;
  int n0 = (local % ntx) << 5;
  int k0 = (local / ntx) << 5;
  __shared__ float tile[32][33];
  int tx = threadIdx.x & 31, ty = threadIdx.x >> 5;
  #pragma unroll
  for (int q = 0; q < 4; q++) {
    int k = k0 + ty + q * 8, n = n0 + tx;
    tile[ty + q * 8][tx] = (k < jb.K && n < jb.N) ? jb.src[(size_t)k * jb.N + n] : 0.f;
  }
  __syncthreads();
  #pragma unroll
  for (int q = 0; q < 4; q++)
    jb.dst[(size_t)(n0 + ty + q * 8) * jb.Kout + k0 + tx] = f2b(tile[tx][ty + q * 8]);
}

__global__ void b16conv_kernel(const float* __restrict__ in, u16* __restrict__ out, int n) {
  int i = blockIdx.x * 256 + threadIdx.x;
  if (i < n) out[i] = f2b(in[i]);
}

// ---------------- pad head biases ----------------
struct PBias { const float* b1[4]; const float* b2[4]; int dh[4]; int dout[4]; };
__global__ void pad_bias_kernel(PBias pb, float* __restrict__ b1p, float* __restrict__ b2p) {
  int t = threadIdx.x;
  for (int hd = 0; hd < 4; hd++) {
    for (int c = t; c < 288; c += 256) b1p[hd * 288 + c] = (c < pb.dh[hd]) ? pb.b1[hd][c] : 0.f;
    for (int c = t; c < 64; c += 256)  b2p[hd * 64 + c] = (c < pb.dout[hd]) ? pb.b2[hd][c] : 0.f;
  }
}

// ---------------- bf16 MFMA GEMM: C = act(A[M,K] @ Bt[N,K]^T + bias) ----------------
// BM=128, BK=32, 256 threads, 4 waves (2x2).
// flags: 1 = Cf += v, 2 = gelu, 4 = Cf = v, 8 = Cb(bf16) = v, 16 = Cf2[row*58+col+coff2] = v.
template<int BN>
__global__ __launch_bounds__(256, 2) void mgemm_kernel(
    const u16* __restrict__ A, const u16* __restrict__ Bt, const float* __restrict__ bias,
    float* __restrict__ Cf, u16* __restrict__ Cb, int K, int ldc, int flags, int Nreal,
    float* __restrict__ Cf2, int coff2) {
  constexpr int NR = BN / 32;
  __shared__ u16 As[2][128 * 32];
  __shared__ u16 Bs[2][BN * 32];
  const int t = threadIdx.x;
  const int row0 = blockIdx.y * 128;
  const int col0 = blockIdx.x * BN;
  const int lane = t & 63, wv = t >> 6;
  const int wr = wv >> 1, wc = wv & 1;
  const int lr = lane & 15, lk = lane >> 4;

  f32x4 acc[4][NR];
  #pragma unroll
  for (int m = 0; m < 4; m++)
    #pragma unroll
    for (int n = 0; n < NR; n++) acc[m][n] = (f32x4){0.f, 0.f, 0.f, 0.f};

  auto stage = [&](int buf, int kt) {
    #pragma unroll
    for (int r = 0; r < 2; r++) {
      int c = t + 256 * r;
      gload16(A + (size_t)(row0 + (c >> 2)) * K + kt + (c & 3) * 8, &As[buf][c * 8]);
    }
    for (int c = t; c < BN * 4; c += 256)
      gload16(Bt + (size_t)(col0 + (c >> 2)) * K + kt + (c & 3) * 8, &Bs[buf][c * 8]);
  };

  stage(0, 0);
  const int nt = K >> 5;
  const int abase = (wr * 64 + lr) * 32 + lk * 8;
  const int bbase = (wc * (BN / 2) + lr) * 32 + lk * 8;
  for (int tile = 0; tile < nt; tile++) {
    __syncthreads();
    int cur = tile & 1;
    if (tile + 1 < nt) stage(cur ^ 1, (tile + 1) * 32);
    bf16x8 af[4], bfr[NR];
    #pragma unroll
    for (int m = 0; m < 4; m++) af[m] = *(const bf16x8*)&As[cur][abase + m * 16 * 32];
    #pragma unroll
    for (int n = 0; n < NR; n++) bfr[n] = *(const bf16x8*)&Bs[cur][bbase + n * 16 * 32];
    #pragma unroll
    for (int m = 0; m < 4; m++)
      #pragma unroll
      for (int n = 0; n < NR; n++)
        acc[m][n] = __builtin_amdgcn_mfma_f32_16x16x32_bf16(af[m], bfr[n], acc[m][n], 0, 0, 0);
  }
  #pragma unroll
  for (int m = 0; m < 4; m++) {
    int row = row0 + wr * 64 + m * 16 + lk * 4;
    #pragma unroll
    for (int n = 0; n < NR; n++) {
      int col = col0 + wc * (BN / 2) + n * 16 + lr;
      if (col >= Nreal) continue;
      float bc = bias[col];
      #pragma unroll
      for (int r = 0; r < 4; r++) {
        float v = acc[m][n][r] + bc;
        if (flags & 2) v = 0.5f * v * (1.f + erff(v * 0.70710678118f));
        size_t idx = (size_t)(row + r) * ldc + col;
        if (flags & 1) Cf[idx] += v;
        if (flags & 4) Cf[idx] = v;
        if (flags & 8) Cb[idx] = f2b(v);
        if (flags & 16) Cf2[(size_t)(row + r) * 58 + col + coff2] = v;
      }
    }
  }
}

// ---------------- MFMA flash attention with relative positions ----------------
// 64 q-rows/block (4 waves x 16), KV tiles of 64, K/V reg-prefetch,
// Vt col-block XOR swizzle, P stride 68, Ps aliased onto Qs.
__global__ __launch_bounds__(256, 3) void attn_kernel(
    const u16* __restrict__ qkv,   // [4096,1536] bf16
    const u16* __restrict__ Erb,   // [1024,64] bf16 (this layer)
    u16* __restrict__ y) {         // [4096,512] bf16
  __shared__ u16 Qs[64 * 72];
  __shared__ u16 Ks[64 * 72];
  __shared__ u16 Vt[64 * 72];
  __shared__ u16 Es[128 * 72];
  u16* const Ps = Qs;  // Q consumed into regs before loop; reuse as P (stride 68)

  const int qi = (int)gridDim.x - 1 - (int)blockIdx.x;  // heavy blocks first
  const int L0 = qi * 64;
  const int h = blockIdx.y, b = blockIdx.z;
  const int t = threadIdx.x, lane = t & 63, w = t >> 6;
  const int lr = lane & 15, lk = lane >> 4;
  const size_t base = (size_t)b * 1024 * 1536;

  #pragma unroll
  for (int r = 0; r < 2; r++) {
    int c = t + 256 * r;
    int qr = c >> 3, ko = c & 7;
    s16x8 v = *(const s16x8*)(qkv + base + (size_t)(L0 + qr) * 1536 + h * 64 + ko * 8);
    *(s16x8*)&Qs[qr * 72 + ko * 8] = v;
  }
  __syncthreads();
  const bf16x8 aq0 = *(const bf16x8*)&Qs[(w * 16 + lr) * 72 + lk * 8];
  const bf16x8 aq1 = *(const bf16x8*)&Qs[(w * 16 + lr) * 72 + lk * 8 + 32];

  const int jr0 = t >> 3, ko0 = t & 7;
  const int jr1 = jr0 + 32;
  const int vswz = (jr0 >> 3) ^ ko0;
  s16x8 kpre[2], vpre[2];
  const u16* const kgb = qkv + base + 512 + h * 64 + ko0 * 8;
  const u16* const vgb = qkv + base + 1024 + h * 64 + ko0 * 8;
  auto prefetch = [&](int j0) {
    kpre[0] = *(const s16x8*)(kgb + (size_t)(j0 + jr0) * 1536);
    kpre[1] = *(const s16x8*)(kgb + (size_t)(j0 + jr1) * 1536);
    vpre[0] = *(const s16x8*)(vgb + (size_t)(j0 + jr0) * 1536);
    vpre[1] = *(const s16x8*)(vgb + (size_t)(j0 + jr1) * 1536);
  };
  prefetch(0);

  f32x4 acc_o[4];
  float mrow[4], srow[4];
  #pragma unroll
  for (int n = 0; n < 4; n++) acc_o[n] = (f32x4){0.f, 0.f, 0.f, 0.f};
  #pragma unroll
  for (int r = 0; r < 4; r++) { mrow[r] = -INFINITY; srow[r] = 0.f; }

  const int lq0 = L0 + w * 16;
  const int ntiles = qi + 1;
  const f32x4 z4 = (f32x4){0.f, 0.f, 0.f, 0.f};

  for (int tt = 0; tt < ntiles; tt++) {
    const int j0 = tt * 64;
    __syncthreads();
    // fill LDS from prefetched K/V regs
    *(s16x8*)&Ks[jr0 * 72 + ko0 * 8] = kpre[0];
    *(s16x8*)&Ks[jr1 * 72 + ko0 * 8] = kpre[1];
    #pragma unroll
    for (int q = 0; q < 8; q++) {
      int d = ko0 * 8 + q;
      Vt[d * 72 + ((vswz & 7) << 3) + (jr0 & 7)] = (u16)vpre[0][q];
      Vt[d * 72 + (((vswz ^ 4) & 7) << 3) + (jr0 & 7)] = (u16)vpre[1][q];
    }
    // Er window (direct stage; Erb is L2-hot)
    const int rb0 = 960 - L0 + j0;
    #pragma unroll
    for (int r = 0; r < 4; r++) {
      int c = t + 256 * r;
      int rb = rb0 + (c >> 3);
      s16x8 ev = {0, 0, 0, 0, 0, 0, 0, 0};
      if (rb < 1024) ev = *(const s16x8*)(Erb + (size_t)rb * 64 + (c & 7) * 8);
      *(s16x8*)&Es[(c >> 3) * 72 + (c & 7) * 8] = ev;
    }
    if (tt + 1 < ntiles) prefetch(j0 + 64);
    __syncthreads();

    f32x4 sacc[4], gacc[5];
    #pragma unroll
    for (int n = 0; n < 4; n++) {
      bf16x8 b0 = *(const bf16x8*)&Ks[(n * 16 + lr) * 72 + lk * 8];
      bf16x8 b1 = *(const bf16x8*)&Ks[(n * 16 + lr) * 72 + lk * 8 + 32];
      sacc[n] = __builtin_amdgcn_mfma_f32_16x16x32_bf16(aq0, b0, z4, 0, 0, 0);
      sacc[n] = __builtin_amdgcn_mfma_f32_16x16x32_bf16(aq1, b1, sacc[n], 0, 0, 0);
    }
    #pragma unroll
    for (int g = 0; g < 5; g++) {
      int er = 48 - 16 * w + g * 16 + lr;
      bf16x8 b0 = *(const bf16x8*)&Es[er * 72 + lk * 8];
      bf16x8 b1 = *(const bf16x8*)&Es[er * 72 + lk * 8 + 32];
      gacc[g] = __builtin_amdgcn_mfma_f32_16x16x32_bf16(aq0, b0, z4, 0, 0, 0);
      gacc[g] = __builtin_amdgcn_mfma_f32_16x16x32_bf16(aq1, b1, gacc[g], 0, 0, 0);
    }

    const bool tile_masked = (j0 + 63 > lq0);
    float pv[4][4], corr[4];
    #pragma unroll
    for (int reg = 0; reg < 4; reg++) {
      int s = 15 - (lk * 4 + reg) + lr;
      int srcl = (lane & 48) | (s & 15);
      int gadd = s >> 4;
      float sh[5];
      #pragma unroll
      for (int g = 0; g < 5; g++) sh[g] = __shfl(gacc[g][reg], srcl, 64);
      int l_abs = lq0 + lk * 4 + reg;
      float sv[4];
      #pragma unroll
      for (int n = 0; n < 4; n++) {
        float gv = gadd ? sh[n + 1] : sh[n];
        float x = (sacc[n][reg] + gv) * 0.125f;
        int j_abs = j0 + n * 16 + lr;
        sv[n] = (tile_masked && j_abs > l_abs) ? -3.0e38f : x;
      }
      float mx = fmaxf(fmaxf(sv[0], sv[1]), fmaxf(sv[2], sv[3]));
      #pragma unroll
      for (int o = 1; o < 16; o <<= 1) mx = fmaxf(mx, __shfl_xor(mx, o, 64));
      float mnew = fmaxf(mrow[reg], mx);
      float cr = __expf(mrow[reg] - mnew);
      mrow[reg] = mnew;
      corr[reg] = cr;
      float ps = 0.f;
      #pragma unroll
      for (int n = 0; n < 4; n++) { float p = __expf(sv[n] - mnew); pv[reg][n] = p; ps += p; }
      #pragma unroll
      for (int o = 1; o < 16; o <<= 1) ps += __shfl_xor(ps, o, 64);
      srow[reg] = srow[reg] * cr + ps;
    }
    #pragma unroll
    for (int reg = 0; reg < 4; reg++) {
      int prow = w * 16 + lk * 4 + reg;
      #pragma unroll
      for (int n = 0; n < 4; n++) Ps[prow * 68 + n * 16 + lr] = f2b(pv[reg][n]);
    }
    #pragma unroll
    for (int n = 0; n < 4; n++) {
      f32x4 o = acc_o[n];
      #pragma unroll
      for (int reg = 0; reg < 4; reg++) o[reg] *= corr[reg];
      acc_o[n] = o;
    }
    union UPS { s16x4 h[2]; bf16x8 v; };
    const int pb = (w * 16 + lr) * 68 + lk * 8;
    UPS u0, u1;
    u0.h[0] = *(const s16x4*)&Ps[pb];
    u0.h[1] = *(const s16x4*)&Ps[pb + 4];
    u1.h[0] = *(const s16x4*)&Ps[pb + 32];
    u1.h[1] = *(const s16x4*)&Ps[pb + 36];
    #pragma unroll
    for (int n = 0; n < 4; n++) {
      int dv = n * 16 + lr;
      int bs = (dv >> 3) & 7;
      bf16x8 b0 = *(const bf16x8*)&Vt[dv * 72 + ((lk ^ bs) << 3)];
      bf16x8 b1 = *(const bf16x8*)&Vt[dv * 72 + ((((lk + 4) ^ bs) & 7) << 3)];
      acc_o[n] = __builtin_amdgcn_mfma_f32_16x16x32_bf16(u0.v, b0, acc_o[n], 0, 0, 0);
      acc_o[n] = __builtin_amdgcn_mfma_f32_16x16x32_bf16(u1.v, b1, acc_o[n], 0, 0, 0);
    }
  }
  #pragma unroll
  for (int reg = 0; reg < 4; reg++) {
    float inv = 1.0f / srow[reg];
    int row = b * 1024 + lq0 + lk * 4 + reg;
    #pragma unroll
    for (int n = 0; n < 4; n++)
      y[(size_t)row * 512 + h * 64 + n * 16 + lr] = f2b(acc_o[n][reg] * inv);
  }
}

extern "C" void kernel_launch(void* const* d_in, const int* in_sizes, int n_in,
                              void* d_out, int out_size, void* d_ws, size_t ws_size,
                              hipStream_t stream) {
  const int* stage = (const int*)d_in[0];
  const int* egoc  = (const int*)d_in[1];
  const int* oppc  = (const int*)d_in[2];
  const int* egoa  = (const int*)d_in[3];
  const int* oppa  = (const int*)d_in[4];
  const float* gamestate  = (const float*)d_in[5];
  const float* controller = (const float*)d_in[6];
  const float* emb_stage  = (const float*)d_in[7];
  const float* emb_char   = (const float*)d_in[8];
  const float* emb_action = (const float*)d_in[9];
  const float* Wd = (const float*)d_in[10];
  const float* bd = (const float*)d_in[11];
  const float* ln1w = (const float*)d_in[12];
  const float* ln1b = (const float*)d_in[13];
  const float* Wqkv = (const float*)d_in[14];
  const float* bqkv = (const float*)d_in[15];
  const float* Wo = (const float*)d_in[16];
  const float* bo = (const float*)d_in[17];
  const float* Er = (const float*)d_in[18];
  const float* ln2w = (const float*)d_in[19];
  const float* ln2b = (const float*)d_in[20];
  const float* Wfc = (const float*)d_in[21];
  const float* bfc = (const float*)d_in[22];
  const float* Wp = (const float*)d_in[23];
  const float* bp = (const float*)d_in[24];
  const float* lnfw = (const float*)d_in[25];
  const float* lnfb = (const float*)d_in[26];

  char* wsb = (char*)d_ws;
  float* x    = (float*)(wsb + 0);             // [4096,512] f32
  float* xcat = (float*)(wsb + 8388608);       // [4096,576] f32
  u16* hb     = (u16*)(wsb + 17825792);        // [4096,512] bf16
  u16* qkvb   = (u16*)(wsb + 22020096);        // [4096,1536] bf16 (alias: hlnb)
  u16* yb     = (u16*)(wsb + 34603008);        // [4096,512] bf16 (alias: hhb)
  u16* ffb    = (u16*)(wsb + 38797312);        // [4096,2048] bf16 (alias: xinb)
  u16* erb    = (u16*)(wsb + 55574528);        // [6,1024,64] bf16
  u16* wt1    = (u16*)(wsb + 56360960);        // [1536,512]
  u16* wt2    = (u16*)(wsb + 57933824);        // [512,512]
  u16* wt3    = (u16*)(wsb + 58458112);        // [2048,512]
  u16* wt4    = (u16*)(wsb + 60555264);        // [512,2048]
  u16* wdt    = (u16*)(wsb + 62652416);        // [512,224]
  u16* w1t    = (u16*)(wsb + 62881792);        // 4 x [288,576]
  u16* w2t    = (u16*)(wsb + 64208896);        // 4 x [64,288]
  float* b1p  = (float*)(wsb + 64356352);      // 4 x 288
  float* b2p  = (float*)(wsb + 64360960);      // 4 x 64
  u16* wall   = (u16*)(wsb + 64365056);        // optional: 6 layers' transposed weights
  u16* xinb   = ffb;
  u16* hlnb   = qkvb;
  u16* hhb    = yb;
  float* out  = (float*)d_out;

  const size_t LSTR = 3145728;  // u16 per layer in wall
  const bool big = ws_size >= (size_t)(64365056 + 6 * LSTR * 2);

  const float* hp[24];
  for (int k = 0; k < 24; k++) hp[k] = (const float*)d_in[27 + k];
  const int din[4]  = {512, 533, 554, 566};
  const int dh[4]   = {256, 266, 277, 283};
  const int dout[4] = {21, 21, 12, 4};

  auto addJob = [](TJobs& J, const float* src, u16* dst, int K, int N, int Kout, int Nout) {
    int i = J.njobs;
    J.j[i].src = src; J.j[i].dst = dst;
    J.j[i].K = K; J.j[i].N = N; J.j[i].Kout = Kout; J.j[i].Nout = Nout;
    J.j[i].start = (i == 0) ? 0
                 : J.j[i - 1].start + (J.j[i - 1].Nout >> 5) * (J.j[i - 1].Kout >> 5);
    J.njobs = i + 1;
  };
  auto jblocks = [](const TJobs& J) {
    const TJob& l = J.j[J.njobs - 1];
    return l.start + (l.Nout >> 5) * (l.Kout >> 5);
  };

  // ---- prep ----
  embed_kernel<<<4096, 256, 0, stream>>>(stage, egoc, oppc, egoa, oppa, gamestate,
                                         controller, emb_stage, emb_char, emb_action, xinb);
  b16conv_kernel<<<1536, 256, 0, stream>>>(Er, erb, 6 * 1024 * 64);
  {
    TJobs J; J.njobs = 0;
    addJob(J, Wd, wdt, 200, 512, 224, 512);
    for (int hd = 0; hd < 4; hd++)
      addJob(J, hp[hd * 6 + 2], w1t + hd * 288 * 576, din[hd], dh[hd], 576, 288);
    for (int hd = 0; hd < 4; hd++)
      addJob(J, hp[hd * 6 + 4], w2t + hd * 64 * 288, dh[hd], dout[hd], 288, 64);
    multi_tpose<<<jblocks(J), 256, 0, stream>>>(J);
  }
  if (big) {
    TJobs J; J.njobs = 0;
    for (int i = 0; i < 6; i++) {
      addJob(J, Wqkv + (size_t)i * 512 * 1536, wall + i * LSTR,           512, 1536, 512, 1536);
      addJob(J, Wo   + (size_t)i * 512 * 512,  wall + i * LSTR + 786432,  512, 512,  512, 512);
      addJob(J, Wfc  + (size_t)i * 512 * 2048, wall + i * LSTR + 1048576, 512, 2048, 512, 2048);
      addJob(J, Wp   + (size_t)i * 2048 * 512, wall + i * LSTR + 2097152, 2048, 512, 2048, 512);
    }
    multi_tpose<<<jblocks(J), 256, 0, stream>>>(J);
  }
  {
    PBias pb;
    for (int hd = 0; hd < 4; hd++) {
      pb.b1[hd] = hp[hd * 6 + 3]; pb.b2[hd] = hp[hd * 6 + 5];
      pb.dh[hd] = dh[hd]; pb.dout[hd] = dout[hd];
    }
    pad_bias_kernel<<<1, 256, 0, stream>>>(pb, b1p, b2p);
  }
  mgemm_kernel<128><<<dim3(4, 32), 256, 0, stream>>>(xinb, wdt, bd, x, nullptr,
                                                     224, 512, 4, 1 << 30, nullptr, 0);

  // ---- transformer layers ----
  for (int i = 0; i < 6; i++) {
    const u16 *W1p, *W2p, *W3p, *W4p;
    if (big) {
      W1p = wall + i * LSTR;
      W2p = wall + i * LSTR + 786432;
      W3p = wall + i * LSTR + 1048576;
      W4p = wall + i * LSTR + 2097152;
    } else {
      TJobs J; J.njobs = 0;
      addJob(J, Wqkv + (size_t)i * 512 * 1536, wt1, 512, 1536, 512, 1536);
      addJob(J, Wo + (size_t)i * 512 * 512, wt2, 512, 512, 512, 512);
      addJob(J, Wfc + (size_t)i * 512 * 2048, wt3, 512, 2048, 512, 2048);
      addJob(J, Wp + (size_t)i * 2048 * 512, wt4, 2048, 512, 2048, 512);
      multi_tpose<<<jblocks(J), 256, 0, stream>>>(J);
      W1p = wt1; W2p = wt2; W3p = wt3; W4p = wt4;
    }
    ln512_kernel<<<1024, 256, 0, stream>>>(x, hb, ln1w + i * 512, ln1b + i * 512);
    mgemm_kernel<128><<<dim3(12, 32), 256, 0, stream>>>(hb, W1p, bqkv + i * 1536,
                                                        nullptr, qkvb, 512, 1536, 8, 1 << 30, nullptr, 0);
    attn_kernel<<<dim3(16, 8, 4), 256, 0, stream>>>(qkvb, erb + (size_t)i * 1024 * 64, yb);
    mgemm_kernel<64><<<dim3(8, 32), 256, 0, stream>>>(yb, W2p, bo + i * 512,
                                                      x, nullptr, 512, 512, 1, 1 << 30, nullptr, 0);
    ln512_kernel<<<1024, 256, 0, stream>>>(x, hb, ln2w + i * 512, ln2b + i * 512);
    mgemm_kernel<128><<<dim3(16, 32), 256, 0, stream>>>(hb, W3p, bfc + i * 2048,
                                                        nullptr, ffb, 512, 2048, 2 | 8, 1 << 30, nullptr, 0);
    mgemm_kernel<64><<<dim3(8, 32), 256, 0, stream>>>(ffb, W4p, bp + i * 512,
                                                      x, nullptr, 2048, 512, 1, 1 << 30, nullptr, 0);
  }

  // ---- final LN + heads (extract fused into GEMM2 epilogue) ----
  ln_kernel<float><<<1024, 256, 0, stream>>>(x, 512, xcat, 576, lnfw, lnfb, 512, 512);
  int col = 512;
  for (int hd = 0; hd < 4; hd++) {
    ln_kernel<u16><<<1024, 256, 0, stream>>>(xcat, 576, hlnb, 576,
                                             hp[hd * 6 + 0], hp[hd * 6 + 1], din[hd], 576);
    mgemm_kernel<96><<<dim3(3, 32), 256, 0, stream>>>(hlnb, w1t + hd * 288 * 576, b1p + hd * 288,
                                                      nullptr, hhb, 576, 288, 2 | 8, 1 << 30, nullptr, 0);
    mgemm_kernel<64><<<dim3(1, 32), 256, 0, stream>>>(hhb, w2t + hd * 64 * 288, b2p + hd * 64,
                                                      xcat + col, nullptr, 288, 576, 4 | 16, dout[hd],
                                                      out, col - 512);
    col += dout[hd];
  }
}

// Round 8
// 1237.835 us; speedup vs baseline: 7.6988x; 1.2242x over previous
//
#include <hip/hip_runtime.h>
#include <math.h>

typedef unsigned short u16;
typedef __bf16 bf16x8 __attribute__((ext_vector_type(8)));
typedef short s16x8 __attribute__((ext_vector_type(8)));
typedef short s16x4 __attribute__((ext_vector_type(4)));
typedef float f32x4 __attribute__((ext_vector_type(4)));

__device__ __forceinline__ u16 f2b(float f) {
  union { float f; unsigned u; } x; x.f = f;
  unsigned r = x.u + 0x7fff + ((x.u >> 16) & 1);
  return (u16)(r >> 16);
}

__device__ __forceinline__ void gload16(const void* g, void* l) {
  __builtin_amdgcn_global_load_lds((const __attribute__((address_space(1))) unsigned int*)g,
                                   (__attribute__((address_space(3))) unsigned int*)l, 16, 0, 0);
}

// ---------------- embedding concat -> bf16, zero-padded to 224 cols ----------------
__global__ void embed_kernel(const int* __restrict__ stage, const int* __restrict__ egoc,
                             const int* __restrict__ oppc, const int* __restrict__ egoa,
                             const int* __restrict__ oppa,
                             const float* __restrict__ gamestate, const float* __restrict__ controller,
                             const float* __restrict__ emb_stage, const float* __restrict__ emb_char,
                             const float* __restrict__ emb_action,
                             u16* __restrict__ xinb) {
  int t = blockIdx.x;
  int c = threadIdx.x;
  if (c >= 224) return;
  float v = 0.f;
  if (c < 8)        v = emb_stage[stage[t] * 8 + c];
  else if (c < 24)  v = emb_char[egoc[t] * 16 + (c - 8)];
  else if (c < 40)  v = emb_char[oppc[t] * 16 + (c - 24)];
  else if (c < 72)  v = emb_action[egoa[t] * 32 + (c - 40)];
  else if (c < 104) v = emb_action[oppa[t] * 32 + (c - 72)];
  else if (c < 168) v = gamestate[t * 64 + (c - 104)];
  else if (c < 200) v = controller[t * 32 + (c - 168)];
  xinb[t * 224 + c] = f2b(v);
}

// ---------------- generic layernorm (one wave per row); T = float or u16 ----------------
template<typename T>
__global__ void ln_kernel(const float* __restrict__ in, int ldi,
                          T* __restrict__ out, int ldo,
                          const float* __restrict__ w, const float* __restrict__ b,
                          int d, int dpad) {
  int wid = threadIdx.x >> 6;
  int lane = threadIdx.x & 63;
  int row = blockIdx.x * 4 + wid;
  const float* ip = in + (size_t)row * ldi;
  float v[9];
  int n = 0;
  float s = 0.f;
  for (int c = lane; c < d; c += 64) { v[n] = ip[c]; s += v[n]; n++; }
  #pragma unroll
  for (int o = 32; o; o >>= 1) s += __shfl_xor(s, o);
  float mu = s / (float)d;
  float q = 0.f;
  for (int i = 0; i < n; i++) { float t = v[i] - mu; q += t * t; }
  #pragma unroll
  for (int o = 32; o; o >>= 1) q += __shfl_xor(q, o);
  float rstd = rsqrtf(q / (float)d + 1e-5f);
  T* op = out + (size_t)row * ldo;
  int c = lane;
  for (int i = 0; i < n; i++, c += 64) {
    float val = (v[i] - mu) * rstd * w[c] + b[c];
    if constexpr (sizeof(T) == 2) op[c] = f2b(val); else op[c] = val;
  }
  for (int cz = (d & ~63) + lane; cz < dpad; cz += 64)
    if (cz >= d) { if constexpr (sizeof(T) == 2) op[cz] = 0; else op[cz] = 0.f; }
}

// ---------------- vectorized LN for d=512, f32 in -> bf16 out (ld 512) ----------------
__global__ void ln512_kernel(const float* __restrict__ in, u16* __restrict__ out,
                             const float* __restrict__ w, const float* __restrict__ b) {
  int wid = threadIdx.x >> 6, lane = threadIdx.x & 63;
  int row = blockIdx.x * 4 + wid;
  const float4* ip = (const float4*)(in + (size_t)row * 512);
  float4 x0 = ip[lane], x1 = ip[lane + 64];
  float s = x0.x + x0.y + x0.z + x0.w + x1.x + x1.y + x1.z + x1.w;
  #pragma unroll
  for (int o = 32; o; o >>= 1) s += __shfl_xor(s, o);
  float mu = s * (1.f / 512.f);
  float q = (x0.x-mu)*(x0.x-mu) + (x0.y-mu)*(x0.y-mu) + (x0.z-mu)*(x0.z-mu) + (x0.w-mu)*(x0.w-mu)
          + (x1.x-mu)*(x1.x-mu) + (x1.y-mu)*(x1.y-mu) + (x1.z-mu)*(x1.z-mu) + (x1.w-mu)*(x1.w-mu);
  #pragma unroll
  for (int o = 32; o; o >>= 1) q += __shfl_xor(q, o);
  float rstd = rsqrtf(q * (1.f / 512.f) + 1e-5f);
  const float4* w4 = (const float4*)w;
  const float4* b4 = (const float4*)b;
  float4 w0 = w4[lane], w1 = w4[lane + 64], c0 = b4[lane], c1 = b4[lane + 64];
  ushort4 o0, o1;
  o0.x = f2b((x0.x - mu) * rstd * w0.x + c0.x);
  o0.y = f2b((x0.y - mu) * rstd * w0.y + c0.y);
  o0.z = f2b((x0.z - mu) * rstd * w0.z + c0.z);
  o0.w = f2b((x0.w - mu) * rstd * w0.w + c0.w);
  o1.x = f2b((x1.x - mu) * rstd * w1.x + c1.x);
  o1.y = f2b((x1.y - mu) * rstd * w1.y + c1.y);
  o1.z = f2b((x1.z - mu) * rstd * w1.z + c1.z);
  o1.w = f2b((x1.w - mu) * rstd * w1.w + c1.w);
  *(ushort4*)(out + (size_t)row * 512 + lane * 4) = o0;
  *(ushort4*)(out + (size_t)row * 512 + 256 + lane * 4) = o1;
}

// ---------------- multi-job weight transpose+convert: in[K,N] f32 -> out[Nout,Kout] bf16 ----
struct TJob { const float* src; u16* dst; int K, N, Kout, Nout, start; };
struct TJobs { TJob j[26]; int njobs; };

__global__ void multi_tpose(TJobs jobs) {
  int bid = blockIdx.x;
  int ji = 0;
  while (ji + 1 < jobs.njobs && bid >= jobs.j[ji + 1].start) ji++;
  TJob jb = jobs.j[ji];
  int local = bid - jb.start;
  int ntx = jb.Nout >> 5;
  int n0 = (local % ntx) << 5;
  int k0 = (local / ntx) << 5;
  __shared__ float tile[32][33];
  int tx = threadIdx.x & 31, ty = threadIdx.x >> 5;
  #pragma unroll
  for (int q = 0; q < 4; q++) {
    int k = k0 + ty + q * 8, n = n0 + tx;
    tile[ty + q * 8][tx] = (k < jb.K && n < jb.N) ? jb.src[(size_t)k * jb.N + n] : 0.f;
  }
  __syncthreads();
  #pragma unroll
  for (int q = 0; q < 4; q++)
    jb.dst[(size_t)(n0 + ty + q * 8) * jb.Kout + k0 + tx] = f2b(tile[tx][ty + q * 8]);
}

__global__ void b16conv_kernel(const float* __restrict__ in, u16* __restrict__ out, int n) {
  int i = blockIdx.x * 256 + threadIdx.x;
  if (i < n) out[i] = f2b(in[i]);
}

// ---------------- pad head biases ----------------
struct PBias { const float* b1[4]; const float* b2[4]; int dh[4]; int dout[4]; };
__global__ void pad_bias_kernel(PBias pb, float* __restrict__ b1p, float* __restrict__ b2p) {
  int t = threadIdx.x;
  for (int hd = 0; hd < 4; hd++) {
    for (int c = t; c < 288; c += 256) b1p[hd * 288 + c] = (c < pb.dh[hd]) ? pb.b1[hd][c] : 0.f;
    for (int c = t; c < 64; c += 256)  b2p[hd * 64 + c] = (c < pb.dout[hd]) ? pb.b2[hd][c] : 0.f;
  }
}

// ---------------- bf16 MFMA GEMM: C = act(A[M,K] @ Bt[N,K]^T + bias) ----------------
// BK=32, 256 threads, 4 waves (2x2), wave tile (BM/2) x (BN/2).
// flags: 1 = Cf += v, 2 = gelu, 4 = Cf = v, 8 = Cb(bf16) = v, 16 = Cf2[row*58+col+coff2] = v.
template<int BM, int BN>
__global__ __launch_bounds__(256, 2) void mgemm_kernel(
    const u16* __restrict__ A, const u16* __restrict__ Bt, const float* __restrict__ bias,
    float* __restrict__ Cf, u16* __restrict__ Cb, int K, int ldc, int flags, int Nreal,
    float* __restrict__ Cf2, int coff2) {
  constexpr int NRW = BN / 32;
  constexpr int MRW = BM / 32;
  __shared__ u16 As[2][BM * 32];
  __shared__ u16 Bs[2][BN * 32];
  const int t = threadIdx.x;
  const int row0 = blockIdx.y * BM;
  const int col0 = blockIdx.x * BN;
  const int lane = t & 63, wv = t >> 6;
  const int wr = wv >> 1, wc = wv & 1;
  const int lr = lane & 15, lk = lane >> 4;

  f32x4 acc[MRW][NRW];
  #pragma unroll
  for (int m = 0; m < MRW; m++)
    #pragma unroll
    for (int n = 0; n < NRW; n++) acc[m][n] = (f32x4){0.f, 0.f, 0.f, 0.f};

  auto stage = [&](int buf, int kt) {
    #pragma unroll
    for (int c = t; c < BM * 4; c += 256)
      gload16(A + (size_t)(row0 + (c >> 2)) * K + kt + (c & 3) * 8, &As[buf][c * 8]);
    #pragma unroll
    for (int c = t; c < BN * 4; c += 256)
      gload16(Bt + (size_t)(col0 + (c >> 2)) * K + kt + (c & 3) * 8, &Bs[buf][c * 8]);
  };

  stage(0, 0);
  const int nt = K >> 5;
  const int abase = (wr * (BM / 2) + lr) * 32 + lk * 8;
  const int bbase = (wc * (BN / 2) + lr) * 32 + lk * 8;
  for (int tile = 0; tile < nt; tile++) {
    __syncthreads();
    int cur = tile & 1;
    if (tile + 1 < nt) stage(cur ^ 1, (tile + 1) * 32);
    bf16x8 af[MRW], bfr[NRW];
    #pragma unroll
    for (int m = 0; m < MRW; m++) af[m] = *(const bf16x8*)&As[cur][abase + m * 16 * 32];
    #pragma unroll
    for (int n = 0; n < NRW; n++) bfr[n] = *(const bf16x8*)&Bs[cur][bbase + n * 16 * 32];
    #pragma unroll
    for (int m = 0; m < MRW; m++)
      #pragma unroll
      for (int n = 0; n < NRW; n++)
        acc[m][n] = __builtin_amdgcn_mfma_f32_16x16x32_bf16(af[m], bfr[n], acc[m][n], 0, 0, 0);
  }
  #pragma unroll
  for (int m = 0; m < MRW; m++) {
    int row = row0 + wr * (BM / 2) + m * 16 + lk * 4;
    #pragma unroll
    for (int n = 0; n < NRW; n++) {
      int col = col0 + wc * (BN / 2) + n * 16 + lr;
      if (col >= Nreal) continue;
      float bc = bias[col];
      #pragma unroll
      for (int r = 0; r < 4; r++) {
        float v = acc[m][n][r] + bc;
        if (flags & 2) v = 0.5f * v * (1.f + erff(v * 0.70710678118f));
        size_t idx = (size_t)(row + r) * ldc + col;
        if (flags & 1) Cf[idx] += v;
        if (flags & 4) Cf[idx] = v;
        if (flags & 8) Cb[idx] = f2b(v);
        if (flags & 16) Cf2[(size_t)(row + r) * 58 + col + coff2] = v;
      }
    }
  }
}

// ---------------- MFMA flash attention, split-KV ----------------
// Block = 64 q-rows x chunk of <=CHUNK KV-tiles (64 each). If the q-block has
// a single chunk, write normalized y; else write unnormalized O + (m,s) partials.
template<int CHUNK>
__global__ __launch_bounds__(256, 3) void attn_kernel(
    const u16* __restrict__ qkv,   // [4096,1536] bf16
    const u16* __restrict__ Erb,   // [1024,64] bf16 (this layer)
    u16* __restrict__ y,           // [4096,512] bf16
    float* __restrict__ part_o,    // [slot][64][64] f32
    float* __restrict__ part_ms) { // [slot][2][64] f32
  __shared__ u16 Qs[64 * 72];
  __shared__ u16 Ks[64 * 72];
  __shared__ u16 Vt[64 * 72];
  __shared__ u16 Es[128 * 72];   // full 128-row window: waves 2-3 read rows 0..31 (R7 bug fix)
  u16* const Ps = Qs;  // Q consumed into regs before loop; reuse as P (stride 68)

  // block -> (qi, chunk) mapping, heavy-first
  int bx = (int)gridDim.x - 1 - (int)blockIdx.x;
  int g = 0, basep = 0;
  while (bx >= basep + CHUNK * (g + 1)) { basep += CHUNK * (g + 1); g++; }
  int off = bx - basep;
  const int qi = CHUNK * g + off / (g + 1);
  const int c = off % (g + 1);
  const int t0 = c * CHUNK;
  const int t1 = min(t0 + CHUNK, qi + 1);
  const int nch = qi / CHUNK + 1;

  const int L0 = qi * 64;
  const int h = blockIdx.y, b = blockIdx.z;
  const int t = threadIdx.x, lane = t & 63, w = t >> 6;
  const int lr = lane & 15, lk = lane >> 4;
  const size_t base = (size_t)b * 1024 * 1536;

  #pragma unroll
  for (int r = 0; r < 2; r++) {
    int cc = t + 256 * r;
    int qr = cc >> 3, ko = cc & 7;
    s16x8 v = *(const s16x8*)(qkv + base + (size_t)(L0 + qr) * 1536 + h * 64 + ko * 8);
    *(s16x8*)&Qs[qr * 72 + ko * 8] = v;
  }
  __syncthreads();
  const bf16x8 aq0 = *(const bf16x8*)&Qs[(w * 16 + lr) * 72 + lk * 8];
  const bf16x8 aq1 = *(const bf16x8*)&Qs[(w * 16 + lr) * 72 + lk * 8 + 32];

  const int jr0 = t >> 3, ko0 = t & 7;
  const int jr1 = jr0 + 32;
  const int vswz = (jr0 >> 3) ^ ko0;
  s16x8 kpre[2], vpre[2];
  const u16* const kgb = qkv + base + 512 + h * 64 + ko0 * 8;
  const u16* const vgb = qkv + base + 1024 + h * 64 + ko0 * 8;
  auto prefetch = [&](int j0) {
    kpre[0] = *(const s16x8*)(kgb + (size_t)(j0 + jr0) * 1536);
    kpre[1] = *(const s16x8*)(kgb + (size_t)(j0 + jr1) * 1536);
    vpre[0] = *(const s16x8*)(vgb + (size_t)(j0 + jr0) * 1536);
    vpre[1] = *(const s16x8*)(vgb + (size_t)(j0 + jr1) * 1536);
  };
  prefetch(t0 * 64);

  f32x4 acc_o[4];
  float mrow[4], srow[4];
  #pragma unroll
  for (int n = 0; n < 4; n++) acc_o[n] = (f32x4){0.f, 0.f, 0.f, 0.f};
  #pragma unroll
  for (int r = 0; r < 4; r++) { mrow[r] = -INFINITY; srow[r] = 0.f; }

  const int lq0 = L0 + w * 16;
  const f32x4 z4 = (f32x4){0.f, 0.f, 0.f, 0.f};

  for (int tt = t0; tt < t1; tt++) {
    const int j0 = tt * 64;
    __syncthreads();
    // fill LDS from prefetched K/V regs
    *(s16x8*)&Ks[jr0 * 72 + ko0 * 8] = kpre[0];
    *(s16x8*)&Ks[jr1 * 72 + ko0 * 8] = kpre[1];
    #pragma unroll
    for (int q = 0; q < 8; q++) {
      int d = ko0 * 8 + q;
      Vt[d * 72 + ((vswz & 7) << 3) + (jr0 & 7)] = (u16)vpre[0][q];
      Vt[d * 72 + (((vswz ^ 4) & 7) << 3) + (jr0 & 7)] = (u16)vpre[1][q];
    }
    // Er window: full 128 rows (rows 0..127 of window starting at rb0)
    const int rb0 = 960 - L0 + j0;
    #pragma unroll
    for (int r = 0; r < 4; r++) {
      int cc = t + 256 * r;
      int rr = cc >> 3;                 // 0..127
      int rb = rb0 + rr;
      s16x8 ev = {0, 0, 0, 0, 0, 0, 0, 0};
      if (rb < 1024) ev = *(const s16x8*)(Erb + (size_t)rb * 64 + (cc & 7) * 8);
      *(s16x8*)&Es[rr * 72 + (cc & 7) * 8] = ev;
    }
    if (tt + 1 < t1) prefetch(j0 + 64);
    __syncthreads();

    f32x4 sacc[4], gacc[5];
    #pragma unroll
    for (int n = 0; n < 4; n++) {
      bf16x8 b0 = *(const bf16x8*)&Ks[(n * 16 + lr) * 72 + lk * 8];
      bf16x8 b1 = *(const bf16x8*)&Ks[(n * 16 + lr) * 72 + lk * 8 + 32];
      sacc[n] = __builtin_amdgcn_mfma_f32_16x16x32_bf16(aq0, b0, z4, 0, 0, 0);
      sacc[n] = __builtin_amdgcn_mfma_f32_16x16x32_bf16(aq1, b1, sacc[n], 0, 0, 0);
    }
    #pragma unroll
    for (int g2 = 0; g2 < 5; g2++) {
      int er = 48 - 16 * w + g2 * 16 + lr;
      bf16x8 b0 = *(const bf16x8*)&Es[er * 72 + lk * 8];
      bf16x8 b1 = *(const bf16x8*)&Es[er * 72 + lk * 8 + 32];
      gacc[g2] = __builtin_amdgcn_mfma_f32_16x16x32_bf16(aq0, b0, z4, 0, 0, 0);
      gacc[g2] = __builtin_amdgcn_mfma_f32_16x16x32_bf16(aq1, b1, gacc[g2], 0, 0, 0);
    }

    const bool tile_masked = (j0 + 63 > lq0);
    float pv[4][4], corr[4];
    #pragma unroll
    for (int reg = 0; reg < 4; reg++) {
      int s = 15 - (lk * 4 + reg) + lr;
      int srcl = (lane & 48) | (s & 15);
      int gadd = s >> 4;
      float sh[5];
      #pragma unroll
      for (int g2 = 0; g2 < 5; g2++) sh[g2] = __shfl(gacc[g2][reg], srcl, 64);
      int l_abs = lq0 + lk * 4 + reg;
      float sv[4];
      #pragma unroll
      for (int n = 0; n < 4; n++) {
        float gv = gadd ? sh[n + 1] : sh[n];
        float x = (sacc[n][reg] + gv) * 0.125f;
        int j_abs = j0 + n * 16 + lr;
        sv[n] = (tile_masked && j_abs > l_abs) ? -3.0e38f : x;
      }
      float mx = fmaxf(fmaxf(sv[0], sv[1]), fmaxf(sv[2], sv[3]));
      #pragma unroll
      for (int o = 1; o < 16; o <<= 1) mx = fmaxf(mx, __shfl_xor(mx, o, 64));
      float mnew = fmaxf(mrow[reg], mx);
      float cr = __expf(mrow[reg] - mnew);
      mrow[reg] = mnew;
      corr[reg] = cr;
      float ps = 0.f;
      #pragma unroll
      for (int n = 0; n < 4; n++) { float p = __expf(sv[n] - mnew); pv[reg][n] = p; ps += p; }
      #pragma unroll
      for (int o = 1; o < 16; o <<= 1) ps += __shfl_xor(ps, o, 64);
      srow[reg] = srow[reg] * cr + ps;
    }
    #pragma unroll
    for (int reg = 0; reg < 4; reg++) {
      int prow = w * 16 + lk * 4 + reg;
      #pragma unroll
      for (int n = 0; n < 4; n++) Ps[prow * 68 + n * 16 + lr] = f2b(pv[reg][n]);
    }
    #pragma unroll
    for (int n = 0; n < 4; n++) {
      f32x4 o = acc_o[n];
      #pragma unroll
      for (int reg = 0; reg < 4; reg++) o[reg] *= corr[reg];
      acc_o[n] = o;
    }
    union UPS { s16x4 h[2]; bf16x8 v; };
    const int pb = (w * 16 + lr) * 68 + lk * 8;
    UPS u0, u1;
    u0.h[0] = *(const s16x4*)&Ps[pb];
    u0.h[1] = *(const s16x4*)&Ps[pb + 4];
    u1.h[0] = *(const s16x4*)&Ps[pb + 32];
    u1.h[1] = *(const s16x4*)&Ps[pb + 36];
    #pragma unroll
    for (int n = 0; n < 4; n++) {
      int dv = n * 16 + lr;
      int bs = (dv >> 3) & 7;
      bf16x8 b0 = *(const bf16x8*)&Vt[dv * 72 + ((lk ^ bs) << 3)];
      bf16x8 b1 = *(const bf16x8*)&Vt[dv * 72 + ((((lk + 4) ^ bs) & 7) << 3)];
      acc_o[n] = __builtin_amdgcn_mfma_f32_16x16x32_bf16(u0.v, b0, acc_o[n], 0, 0, 0);
      acc_o[n] = __builtin_amdgcn_mfma_f32_16x16x32_bf16(u1.v, b1, acc_o[n], 0, 0, 0);
    }
  }

  if (nch == 1) {
    #pragma unroll
    for (int reg = 0; reg < 4; reg++) {
      float inv = 1.0f / srow[reg];
      int row = b * 1024 + lq0 + lk * 4 + reg;
      #pragma unroll
      for (int n = 0; n < 4; n++)
        y[(size_t)row * 512 + h * 64 + n * 16 + lr] = f2b(acc_o[n][reg] * inv);
    }
  } else {
    const int slot = ((b * 8 + h) * 16 + qi) * 4 + c;
    #pragma unroll
    for (int reg = 0; reg < 4; reg++) {
      int row64 = w * 16 + lk * 4 + reg;
      if (lr == 0) {
        part_ms[(size_t)slot * 128 + row64] = mrow[reg];
        part_ms[(size_t)slot * 128 + 64 + row64] = srow[reg];
      }
      #pragma unroll
      for (int n = 0; n < 4; n++)
        part_o[(size_t)slot * 4096 + row64 * 64 + n * 16 + lr] = acc_o[n][reg];
    }
  }
}

// ---------------- merge split-KV partials (q-blocks qi>=4) ----------------
__global__ void attn_merge(const float* __restrict__ part_o, const float* __restrict__ part_ms,
                           u16* __restrict__ y) {
  const int qi = 4 + blockIdx.x;
  const int h = blockIdx.y, b = blockIdx.z;
  const int nch = (qi >> 2) + 1;
  const int row = threadIdx.x >> 2;
  const int d0 = (threadIdx.x & 3) << 4;
  const int slotbase = ((b * 8 + h) * 16 + qi) * 4;
  float m = -INFINITY;
  for (int cc = 0; cc < nch; cc++)
    m = fmaxf(m, part_ms[(size_t)(slotbase + cc) * 128 + row]);
  float s = 0.f;
  float o[16];
  #pragma unroll
  for (int k = 0; k < 16; k++) o[k] = 0.f;
  for (int cc = 0; cc < nch; cc++) {
    const size_t sb = (size_t)(slotbase + cc);
    float mc = part_ms[sb * 128 + row];
    float sc = part_ms[sb * 128 + 64 + row];
    float wv = __expf(mc - m);
    s += sc * wv;
    const float4* po = (const float4*)(part_o + sb * 4096 + row * 64 + d0);
    #pragma unroll
    for (int k4 = 0; k4 < 4; k4++) {
      float4 v = po[k4];
      o[k4 * 4 + 0] += v.x * wv;
      o[k4 * 4 + 1] += v.y * wv;
      o[k4 * 4 + 2] += v.z * wv;
      o[k4 * 4 + 3] += v.w * wv;
    }
  }
  float inv = 1.f / s;
  u16* yp = y + (size_t)(b * 1024 + qi * 64 + row) * 512 + h * 64 + d0;
  #pragma unroll
  for (int k4 = 0; k4 < 4; k4++) {
    ushort4 wv;
    wv.x = f2b(o[k4 * 4 + 0] * inv);
    wv.y = f2b(o[k4 * 4 + 1] * inv);
    wv.z = f2b(o[k4 * 4 + 2] * inv);
    wv.w = f2b(o[k4 * 4 + 3] * inv);
    *(ushort4*)(yp + k4 * 4) = wv;
  }
}

extern "C" void kernel_launch(void* const* d_in, const int* in_sizes, int n_in,
                              void* d_out, int out_size, void* d_ws, size_t ws_size,
                              hipStream_t stream) {
  const int* stage = (const int*)d_in[0];
  const int* egoc  = (const int*)d_in[1];
  const int* oppc  = (const int*)d_in[2];
  const int* egoa  = (const int*)d_in[3];
  const int* oppa  = (const int*)d_in[4];
  const float* gamestate  = (const float*)d_in[5];
  const float* controller = (const float*)d_in[6];
  const float* emb_stage  = (const float*)d_in[7];
  const float* emb_char   = (const float*)d_in[8];
  const float* emb_action = (const float*)d_in[9];
  const float* Wd = (const float*)d_in[10];
  const float* bd = (const float*)d_in[11];
  const float* ln1w = (const float*)d_in[12];
  const float* ln1b = (const float*)d_in[13];
  const float* Wqkv = (const float*)d_in[14];
  const float* bqkv = (const float*)d_in[15];
  const float* Wo = (const float*)d_in[16];
  const float* bo = (const float*)d_in[17];
  const float* Er = (const float*)d_in[18];
  const float* ln2w = (const float*)d_in[19];
  const float* ln2b = (const float*)d_in[20];
  const float* Wfc = (const float*)d_in[21];
  const float* bfc = (const float*)d_in[22];
  const float* Wp = (const float*)d_in[23];
  const float* bp = (const float*)d_in[24];
  const float* lnfw = (const float*)d_in[25];
  const float* lnfb = (const float*)d_in[26];

  char* wsb = (char*)d_ws;
  float* x    = (float*)(wsb + 0);             // [4096,512] f32
  float* xcat = (float*)(wsb + 8388608);       // [4096,576] f32
  u16* hb     = (u16*)(wsb + 17825792);        // [4096,512] bf16
  u16* qkvb   = (u16*)(wsb + 22020096);        // [4096,1536] bf16 (alias: hlnb)
  u16* yb     = (u16*)(wsb + 34603008);        // [4096,512] bf16 (alias: hhb)
  u16* ffb    = (u16*)(wsb + 38797312);        // [4096,2048] bf16 (alias: xinb)
  u16* erb    = (u16*)(wsb + 55574528);        // [6,1024,64] bf16
  u16* wt1    = (u16*)(wsb + 56360960);        // [1536,512]
  u16* wt2    = (u16*)(wsb + 57933824);        // [512,512]
  u16* wt3    = (u16*)(wsb + 58458112);        // [2048,512]
  u16* wt4    = (u16*)(wsb + 60555264);        // [512,2048]
  u16* wdt    = (u16*)(wsb + 62652416);        // [512,224]
  u16* w1t    = (u16*)(wsb + 62881792);        // 4 x [288,576]
  u16* w2t    = (u16*)(wsb + 64208896);        // 4 x [64,288]
  float* b1p  = (float*)(wsb + 64356352);      // 4 x 288
  float* b2p  = (float*)(wsb + 64360960);      // 4 x 64
  u16* wall   = (u16*)(wsb + 64365056);        // optional: 6 layers' transposed weights
  u16* xinb   = ffb;
  u16* hlnb   = qkvb;
  u16* hhb    = yb;
  float* out  = (float*)d_out;

  const size_t LSTR = 3145728;  // u16 per layer in wall
  const size_t WALLB = 6 * LSTR * 2;
  const bool big = ws_size >= (size_t)64365056 + WALLB;
  const size_t poff = 64365056 + (big ? WALLB : 0);
  const bool split = ws_size >= poff + 34603008;  // 32MB part_o + 1MB part_ms
  float* part_o  = (float*)(wsb + poff);
  float* part_ms = (float*)(wsb + poff + 33554432);

  const float* hp[24];
  for (int k = 0; k < 24; k++) hp[k] = (const float*)d_in[27 + k];
  const int din[4]  = {512, 533, 554, 566};
  const int dh[4]   = {256, 266, 277, 283};
  const int dout[4] = {21, 21, 12, 4};

  auto addJob = [](TJobs& J, const float* src, u16* dst, int K, int N, int Kout, int Nout) {
    int i = J.njobs;
    J.j[i].src = src; J.j[i].dst = dst;
    J.j[i].K = K; J.j[i].N = N; J.j[i].Kout = Kout; J.j[i].Nout = Nout;
    J.j[i].start = (i == 0) ? 0
                 : J.j[i - 1].start + (J.j[i - 1].Nout >> 5) * (J.j[i - 1].Kout >> 5);
    J.njobs = i + 1;
  };
  auto jblocks = [](const TJobs& J) {
    const TJob& l = J.j[J.njobs - 1];
    return l.start + (l.Nout >> 5) * (l.Kout >> 5);
  };

  // ---- prep ----
  embed_kernel<<<4096, 256, 0, stream>>>(stage, egoc, oppc, egoa, oppa, gamestate,
                                         controller, emb_stage, emb_char, emb_action, xinb);
  b16conv_kernel<<<1536, 256, 0, stream>>>(Er, erb, 6 * 1024 * 64);
  {
    TJobs J; J.njobs = 0;
    addJob(J, Wd, wdt, 200, 512, 224, 512);
    for (int hd = 0; hd < 4; hd++)
      addJob(J, hp[hd * 6 + 2], w1t + hd * 288 * 576, din[hd], dh[hd], 576, 288);
    for (int hd = 0; hd < 4; hd++)
      addJob(J, hp[hd * 6 + 4], w2t + hd * 64 * 288, dh[hd], dout[hd], 288, 64);
    multi_tpose<<<jblocks(J), 256, 0, stream>>>(J);
  }
  if (big) {
    TJobs J; J.njobs = 0;
    for (int i = 0; i < 6; i++) {
      addJob(J, Wqkv + (size_t)i * 512 * 1536, wall + i * LSTR,           512, 1536, 512, 1536);
      addJob(J, Wo   + (size_t)i * 512 * 512,  wall + i * LSTR + 786432,  512, 512,  512, 512);
      addJob(J, Wfc  + (size_t)i * 512 * 2048, wall + i * LSTR + 1048576, 512, 2048, 512, 2048);
      addJob(J, Wp   + (size_t)i * 2048 * 512, wall + i * LSTR + 2097152, 2048, 512, 2048, 512);
    }
    multi_tpose<<<jblocks(J), 256, 0, stream>>>(J);
  }
  {
    PBias pb;
    for (int hd = 0; hd < 4; hd++) {
      pb.b1[hd] = hp[hd * 6 + 3]; pb.b2[hd] = hp[hd * 6 + 5];
      pb.dh[hd] = dh[hd]; pb.dout[hd] = dout[hd];
    }
    pad_bias_kernel<<<1, 256, 0, stream>>>(pb, b1p, b2p);
  }
  mgemm_kernel<64, 64><<<dim3(8, 64), 256, 0, stream>>>(xinb, wdt, bd, x, nullptr,
                                                        224, 512, 4, 1 << 30, nullptr, 0);

  // ---- transformer layers ----
  for (int i = 0; i < 6; i++) {
    const u16 *W1p, *W2p, *W3p, *W4p;
    if (big) {
      W1p = wall + i * LSTR;
      W2p = wall + i * LSTR + 786432;
      W3p = wall + i * LSTR + 1048576;
      W4p = wall + i * LSTR + 2097152;
    } else {
      TJobs J; J.njobs = 0;
      addJob(J, Wqkv + (size_t)i * 512 * 1536, wt1, 512, 1536, 512, 1536);
      addJob(J, Wo + (size_t)i * 512 * 512, wt2, 512, 512, 512, 512);
      addJob(J, Wfc + (size_t)i * 512 * 2048, wt3, 512, 2048, 512, 2048);
      addJob(J, Wp + (size_t)i * 2048 * 512, wt4, 2048, 512, 2048, 512);
      multi_tpose<<<jblocks(J), 256, 0, stream>>>(J);
      W1p = wt1; W2p = wt2; W3p = wt3; W4p = wt4;
    }
    ln512_kernel<<<1024, 256, 0, stream>>>(x, hb, ln1w + i * 512, ln1b + i * 512);
    mgemm_kernel<64, 128><<<dim3(12, 64), 256, 0, stream>>>(hb, W1p, bqkv + i * 1536,
                                                            nullptr, qkvb, 512, 1536, 8, 1 << 30, nullptr, 0);
    if (split) {
      attn_kernel<4><<<dim3(40, 8, 4), 256, 0, stream>>>(qkvb, erb + (size_t)i * 1024 * 64, yb,
                                                         part_o, part_ms);
      attn_merge<<<dim3(12, 8, 4), 256, 0, stream>>>(part_o, part_ms, yb);
    } else {
      attn_kernel<16><<<dim3(16, 8, 4), 256, 0, stream>>>(qkvb, erb + (size_t)i * 1024 * 64, yb,
                                                          x, x);
    }
    mgemm_kernel<64, 64><<<dim3(8, 64), 256, 0, stream>>>(yb, W2p, bo + i * 512,
                                                          x, nullptr, 512, 512, 1, 1 << 30, nullptr, 0);
    ln512_kernel<<<1024, 256, 0, stream>>>(x, hb, ln2w + i * 512, ln2b + i * 512);
    mgemm_kernel<64, 128><<<dim3(16, 64), 256, 0, stream>>>(hb, W3p, bfc + i * 2048,
                                                            nullptr, ffb, 512, 2048, 2 | 8, 1 << 30, nullptr, 0);
    mgemm_kernel<64, 64><<<dim3(8, 64), 256, 0, stream>>>(ffb, W4p, bp + i * 512,
                                                          x, nullptr, 2048, 512, 1, 1 << 30, nullptr, 0);
  }

  // ---- final LN + heads (extract fused into GEMM2 epilogue) ----
  ln_kernel<float><<<1024, 256, 0, stream>>>(x, 512, xcat, 576, lnfw, lnfb, 512, 512);
  int col = 512;
  for (int hd = 0; hd < 4; hd++) {
    ln_kernel<u16><<<1024, 256, 0, stream>>>(xcat, 576, hlnb, 576,
                                             hp[hd * 6 + 0], hp[hd * 6 + 1], din[hd], 576);
    mgemm_kernel<64, 96><<<dim3(3, 64), 256, 0, stream>>>(hlnb, w1t + hd * 288 * 576, b1p + hd * 288,
                                                          nullptr, hhb, 576, 288, 2 | 8, 1 << 30, nullptr, 0);
    mgemm_kernel<64, 64><<<dim3(1, 64), 256, 0, stream>>>(hhb, w2t + hd * 64 * 288, b2p + hd * 64,
                                                          xcat + col, nullptr, 288, 576, 4 | 16, dout[hd],
                                                          out, col - 512);
    col += dout[hd];
  }
}